// Round 6
// baseline (450.412 us; speedup 1.0000x reference)
//
#include <hip/hip_runtime.h>

typedef unsigned short u16;
typedef short short8 __attribute__((ext_vector_type(8)));
typedef float f32x4 __attribute__((ext_vector_type(4)));

#define MF(a,b,c) __builtin_amdgcn_mfma_f32_16x16x32_bf16(a,b,c,0,0,0)

// ---------- bf16 helpers ----------
__device__ __forceinline__ float bu2f(u16 u){
  return __uint_as_float(((unsigned int)u) << 16);
}
__device__ __forceinline__ u16 f2bu(float f){
  unsigned int b = __float_as_uint(f);
  unsigned int r = (b + 0x7FFFu + ((b >> 16) & 1u)) >> 16;  // RNE
  return (u16)r;
}
__device__ __forceinline__ void ld4a(float* d, const float* p){
  float4 v = *(const float4*)p;
  d[0]=v.x; d[1]=v.y; d[2]=v.z; d[3]=v.w;
}
__device__ __forceinline__ void st4(float* p, const float* s){
  *(float4*)p = make_float4(s[0], s[1], s[2], s[3]);
}
__device__ __forceinline__ void ld4b(float* d, const u16* p){
  ushort4 v = *(const ushort4*)p;
  d[0]=bu2f(v.x); d[1]=bu2f(v.y); d[2]=bu2f(v.z); d[3]=bu2f(v.w);
}
__device__ __forceinline__ void st4b(u16* p, const float* s){
  ushort4 v;
  v.x=f2bu(s[0]); v.y=f2bu(s[1]); v.z=f2bu(s[2]); v.w=f2bu(s[3]);
  *(ushort4*)p = v;
}
__device__ __forceinline__ ushort4 pk4(f32x4 v){
  ushort4 u; u.x=f2bu(v[0]); u.y=f2bu(v[1]); u.z=f2bu(v[2]); u.w=f2bu(v[3]); return u;
}
__device__ __forceinline__ short8 mulpk(short8 g, short8 f){
  short8 o;
  #pragma unroll
  for (int e = 0; e < 8; ++e)
    o[e] = (short)f2bu(bu2f((u16)g[e])*bu2f((u16)f[e]));
  return o;
}
// async global->LDS, 16B per lane (dest must be uniform base + lane*16)
__device__ __forceinline__ void gl_lds16(const void* g, void* l){
  __builtin_amdgcn_global_load_lds(
      (const __attribute__((address_space(1))) void*)g,
      (__attribute__((address_space(3))) void*)l, 16, 0, 0);
}

// ---------- workspace layout ----------
#define TABF_RE   0
#define TABF_IM   4096
#define TABIF_RE  8192
#define TABIF_IM  12288
#define TABTW_RE  16384      // exp(+2pi i k1*n2/4096) f32 [k1][n2]
#define TABTW_IM  20480
#define NORMS_OFF 24576
#define MMAT_OFF  26624
#define FLAG_OFF  92160
#define PRM_OFF   92224
#define WT_OFF    94848      // wT2 bf16 conv weights (294912 u16)
#define DFT16_OFF 242304     // bf16 DFT matrices: EFr,EFi,EIr,EIi (4*4096 u16)
#define F32_END   389760
// params sub-offsets:
#define P_CB   0
#define P_BNS  128
#define P_BNB  256
#define P_TEMP 384
#define P_W1   400
#define P_B1   1424
#define P_S1   1432
#define P_BB1  1440
#define P_W2   1456
#define P_B2   2480
// bf16 region:
#define BPLANE    8388608
// x_t aliases Frb+Fib (dead before k_fft2_m writes them); A/g at 2*BPLANE.
// Gram partials (f32, 8 MB) alias the A/g region: A is dead after k_fft2_m,
// and k_gate overwrites g only after k_attn2 consumed the partials.

// ===================== input dtype detection =====================
__global__ void k_detect(const u16* __restrict__ xv, int* __restrict__ flag){
  const int t = threadIdx.x;
  int huge = 0;
  for (int i = 0; i < 16; ++i){
    u16 u = xv[(t*16 + i)*2];
    int e = (u >> 7) & 0xFF;
    huge += (e >= 0xC0) ? 1 : 0;
  }
  #pragma unroll
  for (int off = 32; off > 0; off >>= 1) huge += __shfl_down(huge, off, 64);
  if (t == 0) flag[0] = (huge >= 8) ? 1 : 0;
}

// ===================== tables =====================
__global__ void k_tables(float* ws){
  int idx = blockIdx.x*256 + threadIdx.x;
  int j = idx >> 6, k = idx & 63;
  int jk = j*k;
  float s, c;
  sincospif(-(float)(jk & 63)/32.0f, &s, &c);
  ws[TABF_RE+idx] = c; ws[TABF_IM+idx] = s;
  sincospif((float)(jk & 63)/32.0f, &s, &c);
  ws[TABIF_RE+idx] = c*(1.f/64.f); ws[TABIF_IM+idx] = s*(1.f/64.f);
  sincospif((float)jk/2048.0f, &s, &c);
  ws[TABTW_RE+idx] = c; ws[TABTW_IM+idx] = s;
}

// bf16 DFT matrices (fragment-ready row-major; E is symmetric)
__global__ void k_dftprep(u16* __restrict__ m){
  int idx = blockIdx.x*256 + threadIdx.x;   // 0..4095
  int j = idx >> 6, k = idx & 63;
  int jk = (j*k) & 63;
  float s, c;
  sincospif(-(float)jk/32.0f, &s, &c);
  m[idx]        = f2bu(c);
  m[4096+idx]   = f2bu(s);
  sincospif((float)jk/32.0f, &s, &c);
  m[8192+idx]   = f2bu(c*(1.f/64.f));
  m[12288+idx]  = f2bu(s*(1.f/64.f));
}

// ===================== pack small params -> f32 =====================
__global__ void k_pack(const void* cb, const void* bns, const void* bnb, const void* temp,
                       const void* w1, const void* b1, const void* s1, const void* bb1,
                       const void* w2, const void* b2,
                       const int* __restrict__ flg, float* __restrict__ P){
  const int t = threadIdx.x;
  const int f32 = *flg;
  if (f32){
    for (int i = t; i < 128; i += 256){
      P[P_CB+i]  = ((const float*)cb)[i];
      P[P_BNS+i] = ((const float*)bns)[i];
      P[P_BNB+i] = ((const float*)bnb)[i];
      P[P_B2+i]  = ((const float*)b2)[i];
    }
    for (int i = t; i < 1024; i += 256){
      P[P_W1+i] = ((const float*)w1)[i];
      P[P_W2+i] = ((const float*)w2)[i];
    }
    if (t < 8){
      P[P_TEMP+t] = ((const float*)temp)[t];
      P[P_B1+t]   = ((const float*)b1)[t];
      P[P_S1+t]   = ((const float*)s1)[t];
      P[P_BB1+t]  = ((const float*)bb1)[t];
    }
  } else {
    for (int i = t; i < 128; i += 256){
      P[P_CB+i]  = bu2f(((const u16*)cb)[i]);
      P[P_BNS+i] = bu2f(((const u16*)bns)[i]);
      P[P_BNB+i] = bu2f(((const u16*)bnb)[i]);
      P[P_B2+i]  = bu2f(((const u16*)b2)[i]);
    }
    for (int i = t; i < 1024; i += 256){
      P[P_W1+i] = bu2f(((const u16*)w1)[i]);
      P[P_W2+i] = bu2f(((const u16*)w2)[i]);
    }
    if (t < 8){
      P[P_TEMP+t] = bu2f(((const u16*)temp)[t]);
      P[P_B1+t]   = bu2f(((const u16*)b1)[t]);
      P[P_S1+t]   = bu2f(((const u16*)s1)[t]);
      P[P_BB1+t]  = bu2f(((const u16*)bb1)[t]);
    }
  }
}

// ===================== weight prep for MFMA conv =====================
__global__ void k_wprep2(const void* __restrict__ w, u16* __restrict__ wT2,
                         const float* __restrict__ prm, const int* __restrict__ flg){
  const int f32 = *flg;
  int U = blockIdx.x*256 + threadIdx.x;
  if (U < 294912){
    int j = U & 7;
    int E = U >> 3;
    int n = E & 127;
    int o = (E >> 7) & 3;
    int tc = E >> 9;
    int chunk = tc & 7, tap = tc >> 3;
    int c = chunk*32 + o*8 + j;
    int src = n*2304 + c*9 + tap;
    float v = f32 ? ((const float*)w)[src] : bu2f(((const u16*)w)[src]);
    wT2[U] = f2bu(v * prm[P_BNS + n]);
  }
}

// ===================== x transpose: NCHW -> [b][h][w][c] bf16 =====================
__global__ __launch_bounds__(256) void k_trans(const void* __restrict__ x, u16* __restrict__ xt,
                                               const int* __restrict__ flg){
  __shared__ u16 L[256*66];
  const int t = threadIdx.x;
  const int b = blockIdx.x >> 6, h = blockIdx.x & 63;
  const int f32m = __builtin_amdgcn_readfirstlane(*flg);
  if (f32m){
    const float* xf = (const float*)x;
    for (int i = t; i < 16384; i += 256){
      int c = i >> 6, w = i & 63;
      L[c*66 + w] = f2bu(xf[((b*256 + c)*64 + h)*64 + w]);
    }
  } else {
    const u16* xb = (const u16*)x;
    for (int i = t; i < 16384; i += 256){
      int c = i >> 6, w = i & 63;
      L[c*66 + w] = xb[((b*256 + c)*64 + h)*64 + w];
    }
  }
  __syncthreads();
  u16* dst = xt + ((b*64 + h)*64)*256;
  for (int j = t; j < 16384; j += 256){
    int w = j >> 8, c = j & 255;
    dst[w*256 + c] = L[c*66 + w];
  }
}

// ===================== MFMA implicit-GEMM conv + BN + ReLU =====================
// 512 thr / 8 waves (wave = wrow*2+wcol; wrow = h-row, wcol = 64-ch half).
// __launch_bounds__(512, 2): min 2 waves/EU -> VGPR cap 256 (r5 needs ~168, no spill;
// r2's 88-VGPR spill came from staging regs + unqualified bounds — both gone).
// wcol pair duplicates A-reads WITHIN the CU (L1 hit; r3's cross-CU dup was the
// FETCH explosion). Async gl_lds double-buffer (2x64 KB) + XCD swizzle from r5.
__global__ __launch_bounds__(512, 2) void k_cmm(const u16* __restrict__ xt, const u16* __restrict__ wT2,
                                                const float* __restrict__ prm, u16* __restrict__ A){
  __shared__ __align__(16) uint4 sm4[8192];   // 128 KB = 2 x 64 KB weight buffers
  const int t = threadIdx.x;
  const int blk = blockIdx.x;
  // XCD-aware decode: all 16 mtiles of image bb land on one XCD (xt slice L2-resident)
  const int bb = (blk & 7) + 8*(blk >> 7);
  const int mtile = (blk >> 3) & 15;
  const int h0 = mtile*4;
  const int lane = t & 63, wave = t >> 6;
  const int wrow = wave >> 1, wcol = wave & 1;
  const int quad = lane >> 4, lr = lane & 15;

  f32x4 acc[4][4];
  #pragma unroll
  for (int mi = 0; mi < 4; ++mi)
    #pragma unroll
    for (int j = 0; j < 4; ++j)
      acc[mi][j] = (f32x4){0.f,0.f,0.f,0.f};

  const short8 zz = {0,0,0,0,0,0,0,0};

  // prologue: DMA tap 0 -> buf 0 (zero staging VGPRs)
  {
    const uint4* src = (const uint4*)wT2;
    #pragma unroll
    for (int i = 0; i < 8; ++i) gl_lds16(&src[t + 512*i], &sm4[t + 512*i]);
  }
  __syncthreads();   // vmcnt(0) drain + barrier

  for (int tap = 0; tap < 9; ++tap){
    const int ky = tap/3, kx = tap - ky*3;
    const int buf = tap & 1;

    // issue next tap's DMA into the other buffer (lands under this tap's compute)
    if (tap < 8){
      const uint4* src = (const uint4*)(wT2 + (tap+1)*32768);
      uint4* dst = sm4 + (buf^1)*4096;
      #pragma unroll
      for (int i = 0; i < 8; ++i) gl_lds16(&src[t + 512*i], &dst[t + 512*i]);
    }

    const u16* smB = (const u16*)(sm4 + buf*4096);
    const int hg = h0 + wrow + 3*ky - 3;
    const bool hok = ((unsigned)hg < 64u);
    const u16* abase = xt + ((bb*64 + hg)*64)*256 + quad*8;

    for (int chunk = 0; chunk < 8; ++chunk){
      short8 av[4];
      #pragma unroll
      for (int mi = 0; mi < 4; ++mi){
        const int wg = mi*16 + lr + 3*kx - 3;
        short8 v = zz;
        if (hok && ((unsigned)wg < 64u))
          v = *(const short8*)(abase + wg*256 + chunk*32);
        av[mi] = v;
      }
      short8 bv[4];
      #pragma unroll
      for (int j = 0; j < 4; ++j)
        bv[j] = *(const short8*)(smB + (chunk*512 + quad*128 + (wcol*4+j)*16 + lr)*8);
      #pragma unroll
      for (int mi = 0; mi < 4; ++mi)
        #pragma unroll
        for (int j = 0; j < 4; ++j)
          acc[mi][j] = MF(av[mi], bv[j], acc[mi][j]);
    }
    __syncthreads();   // drains next-tap DMA (vmcnt 0) + syncs buffer swap
  }

  // epilogue: transpose through LDS (sm4 reused, 32x261 f32 = 33.4 KB),
  // 4 rounds of 32 channels (r2/r4's correctness-verified 512-thr epilogue).
  float* C = (float*)sm4;
  u16* outb = A + (bb*128)*4096 + mtile*256;
  const int ch32 = wcol*16 + lr;
  for (int nt2 = 0; nt2 < 4; ++nt2){
    #pragma unroll
    for (int mi = 0; mi < 4; ++mi)
      #pragma unroll
      for (int r = 0; r < 4; ++r){
        const int m = wrow*64 + mi*16 + quad*4 + r;
        C[ch32*261 + m] = acc[mi][nt2][r];
      }
    __syncthreads();
    #pragma unroll
    for (int dd = 0; dd < 16; ++dd){
      const int idx = dd*512 + t;
      const int c32 = idx >> 8, m = idx & 255;
      const int d = (c32 >> 4)*64 + nt2*16 + (c32 & 15);
      const float bi = prm[P_CB + d]*prm[P_BNS + d] + prm[P_BNB + d];
      const float v = fmaxf(C[c32*261 + m] + bi, 0.f);
      outb[d*4096 + m] = f2bu(v);
    }
    __syncthreads();
  }
}

// ===================== fft2 via MFMA: F = E*img*E per (b,c) =====================
__global__ __launch_bounds__(256) void k_fft2_m(const u16* __restrict__ A, u16* __restrict__ Frb,
                                                u16* __restrict__ Fib, const u16* __restrict__ dft){
  __shared__ __align__(16) u16 TTr[64*72], TTi[64*72];
  const int bc = blockIdx.x, t = threadIdx.x;
  const int lane = t & 63, wave = t >> 6;
  const int quad = lane >> 4, lr = lane & 15;
  const u16* EFr = dft;
  const u16* EFi = dft + 4096;
  const u16* img = A + bc*4096;
  // pass1: T[h][k2] = sum_w img[h][w] E[k2][w]; store T^T[k2][h] (k2-tile = wave)
  #pragma unroll
  for (int mi = 0; mi < 4; ++mi){
    f32x4 ar = {0.f,0.f,0.f,0.f}, ai = {0.f,0.f,0.f,0.f};
    #pragma unroll
    for (int ks = 0; ks < 2; ++ks){
      short8 av = *(const short8*)(img + (mi*16+lr)*64 + ks*32 + quad*8);
      short8 br = *(const short8*)(EFr + (wave*16+lr)*64 + ks*32 + quad*8);
      short8 bi = *(const short8*)(EFi + (wave*16+lr)*64 + ks*32 + quad*8);
      ar = MF(av, br, ar); ai = MF(av, bi, ai);
    }
    // D[m=h=mi*16+quad*4+r][n=k2=wave*16+lr]
    *(ushort4*)(TTr + (wave*16+lr)*72 + mi*16 + quad*4) = pk4(ar);
    *(ushort4*)(TTi + (wave*16+lr)*72 + mi*16 + quad*4) = pk4(ai);
  }
  __syncthreads();
  // pass2: F^T[k2][k1] = sum_h T^T[k2][h] E[k1][h]  (k2-tile = wave)
  #pragma unroll
  for (int nt = 0; nt < 4; ++nt){
    f32x4 a1={0.f,0.f,0.f,0.f}, a2={0.f,0.f,0.f,0.f}, a3={0.f,0.f,0.f,0.f}, a4={0.f,0.f,0.f,0.f};
    #pragma unroll
    for (int ks = 0; ks < 2; ++ks){
      short8 tr = *(const short8*)(TTr + (wave*16+lr)*72 + ks*32 + quad*8);
      short8 ti = *(const short8*)(TTi + (wave*16+lr)*72 + ks*32 + quad*8);
      short8 br = *(const short8*)(EFr + (nt*16+lr)*64 + ks*32 + quad*8);
      short8 bi = *(const short8*)(EFi + (nt*16+lr)*64 + ks*32 + quad*8);
      a1 = MF(tr, br, a1); a2 = MF(ti, bi, a2);
      a3 = MF(tr, bi, a3); a4 = MF(ti, br, a4);
    }
    f32x4 fr, fi;
    #pragma unroll
    for (int r = 0; r < 4; ++r){ fr[r] = a1[r]-a2[r]; fi[r] = a3[r]+a4[r]; }
    // D[m=k2=wave*16+quad*4+r][n=k1=nt*16+lr]; flat = k1*64 + k2
    const int flat = (nt*16+lr)*64 + wave*16 + quad*4;
    *(ushort4*)(Frb + bc*4096 + flat) = pk4(fr);
    *(ushort4*)(Fib + bc*4096 + flat) = pk4(fi);
  }
}

// ===================== attention phase 1: split-K MFMA Gram partials =====================
// grid = 128 (b,h) * 16 n-chunks; each wave owns 64 columns (2 K-steps).
// Partials p1=Ar*Ar^T, p2=Ai*Ai^T, p3=Ar*Ai^T, p4=Ai*Ar^T stored raw so that
// phase 2 recovers gr=p1-p2, gi=p3+p4 AND norms^2[i]=(p1+p2)[i][i] (k_norms is gone).
__global__ __launch_bounds__(256) void k_attn1(const u16* __restrict__ Frb,
                                               const u16* __restrict__ Fib,
                                               float* __restrict__ part){
  __shared__ float R[4][4][256];   // [wave][q][m*16+n]
  const int blk = blockIdx.x;
  const int bh = blk >> 4, chunk = blk & 15;
  const int t = threadIdx.x, lane = t & 63, wave = t >> 6;
  const int quad = lane >> 4, lr = lane & 15;
  const u16* fr = Frb + bh*65536;
  const u16* fi = Fib + bh*65536;
  const int c0 = chunk*256 + wave*64;
  f32x4 a1={0.f,0.f,0.f,0.f}, a2={0.f,0.f,0.f,0.f}, a3={0.f,0.f,0.f,0.f}, a4={0.f,0.f,0.f,0.f};
  #pragma unroll
  for (int ks = 0; ks < 2; ++ks){
    const int off = lr*4096 + c0 + ks*32 + quad*8;
    short8 ar = *(const short8*)(fr + off);
    short8 ai = *(const short8*)(fi + off);
    a1 = MF(ar, ar, a1); a2 = MF(ai, ai, a2);
    a3 = MF(ar, ai, a3); a4 = MF(ai, ar, a4);
  }
  // D[m=quad*4+r][n=lr]
  #pragma unroll
  for (int r = 0; r < 4; ++r){
    const int mn = (quad*4 + r)*16 + lr;
    R[wave][0][mn] = a1[r];
    R[wave][1][mn] = a2[r];
    R[wave][2][mn] = a3[r];
    R[wave][3][mn] = a4[r];
  }
  __syncthreads();
  float* dst = part + blk*1024;
  #pragma unroll
  for (int q = 0; q < 4; ++q)
    dst[q*256 + t] = R[0][q][t] + R[1][q][t] + R[2][q][t] + R[3][q][t];
}

// ===================== attention phase 2: reduce + norms + dual softmax + c-axis ifft fold ===
__global__ __launch_bounds__(256) void k_attn2(const float* __restrict__ part,
                                               const float* __restrict__ prm,
                                               float* __restrict__ wsM){
  __shared__ float AR[16][17], AI[16][17], NR[16];
  const int bh = blockIdx.x;
  const int h = bh & 7;
  const int t = threadIdx.x;
  const float* p = part + bh*16384;
  float s1=0.f, s2=0.f, s3=0.f, s4=0.f;
  #pragma unroll
  for (int ch = 0; ch < 16; ++ch){
    s1 += p[ch*1024 +       t];
    s2 += p[ch*1024 + 256 + t];
    s3 += p[ch*1024 + 512 + t];
    s4 += p[ch*1024 + 768 + t];
  }
  const int m = t >> 4, n = t & 15;
  if (m == n) NR[m] = fmaxf(sqrtf(fmaxf(s1 + s2, 0.f)), 1e-12f);
  __syncthreads();
  const float sc = prm[P_TEMP + h] / (NR[m]*NR[n]);
  AR[m][n] = (s1 - s2)*sc;
  AI[m][n] = (s3 + s4)*sc;
  __syncthreads();
  if (t < 32){
    float* row = (t < 16) ? AR[t & 15] : AI[t & 15];
    float mx = row[0];
    for (int j2 = 1; j2 < 16; ++j2) mx = fmaxf(mx, row[j2]);
    float s = 0.f, e[16];
    for (int j2 = 0; j2 < 16; ++j2){ e[j2] = expf(row[j2] - mx); s += e[j2]; }
    float inv = 1.f/s;
    for (int j2 = 0; j2 < 16; ++j2) row[j2] = e[j2]*inv;
  }
  __syncthreads();
  {
    const int mi = t >> 4, mj = t & 15;
    float mr = 0.f, mim = 0.f;
    #pragma unroll
    for (int pp = 0; pp < 16; ++pp){
      float sv, cv;
      sincospif((float)((mi*pp) & 15)/8.0f, &sv, &cv);
      const float arv = AR[pp][mj], aiv = AI[pp][mj];
      mr  += cv*arv - sv*aiv;
      mim += cv*aiv + sv*arv;
    }
    wsM[bh*512 + t*2]     = mr*(1.f/16.f);
    wsM[bh*512 + t*2 + 1] = mim*(1.f/16.f);
  }
}

// ===================== gating MLP -> g plane (bf16) =====================
__global__ __launch_bounds__(256) void k_gate(const u16* __restrict__ Frb,
                                              const float* __restrict__ prm,
                                              u16* __restrict__ g){
  __shared__ float W1T[128][8];
  __shared__ float W2[128][8];
  __shared__ float B1v[8], S1v[8], BB1v[8];
  __shared__ float B2v[128];
  const int t = threadIdx.x;
  for (int i = t; i < 1024; i += 256){
    W1T[i & 127][i >> 7] = prm[P_W1 + i];
    W2[i >> 3][i & 7]    = prm[P_W2 + i];
  }
  if (t < 8){ B1v[t] = prm[P_B1+t]; S1v[t] = prm[P_S1+t]; BB1v[t] = prm[P_BB1+t]; }
  if (t < 128) B2v[t] = prm[P_B2+t];
  __syncthreads();
  const int pix = blockIdx.x*256 + t;
  const int b = pix >> 12, n = pix & 4095;
  const u16* fr = Frb + b*128*4096 + n;
  float q[8] = {};
  for (int c = 0; c < 128; ++c){
    const float v = bu2f(fr[c*4096]);
    float wa[4], wb[4];
    ld4a(wa, &W1T[c][0]); ld4a(wb, &W1T[c][4]);
    #pragma unroll
    for (int k = 0; k < 4; ++k){ q[k] = fmaf(wa[k], v, q[k]); q[4+k] = fmaf(wb[k], v, q[4+k]); }
  }
  float qa[8];
  #pragma unroll
  for (int k = 0; k < 8; ++k)
    qa[k] = fmaxf(fmaf(q[k] + B1v[k], S1v[k], BB1v[k]), 0.f);
  u16* grow = g + b*128*4096 + n;
  for (int c = 0; c < 128; ++c){
    float wa[4], wb[4];
    ld4a(wa, &W2[c][0]); ld4a(wb, &W2[c][4]);
    float acc = B2v[c];
    #pragma unroll
    for (int k = 0; k < 4; ++k) acc += wa[k]*qa[k] + wb[k]*qa[4+k];
    grow[c*4096] = f2bu(1.f/(1.f + expf(-acc)));
  }
}

// ===================== out_l = |ifft2(g*F)| + x via MFMA (channels 128..255) =====================
__global__ __launch_bounds__(256) void k_outl_m(const u16* __restrict__ Frb, const u16* __restrict__ Fib,
                                                const u16* __restrict__ g, const void* __restrict__ x,
                                                float* __restrict__ out, const u16* __restrict__ dft,
                                                const int* __restrict__ flg){
  __shared__ __align__(16) u16 TTr[64*72], TTi[64*72];
  const int bc = blockIdx.x, t = threadIdx.x;
  const int b = bc >> 7, c = bc & 127;
  const int lane = t & 63, wave = t >> 6;
  const int quad = lane >> 4, lr = lane & 15;
  const int f32m = __builtin_amdgcn_readfirstlane(*flg);
  const u16* EIr = dft + 8192;
  const u16* EIi = dft + 12288;
  const u16* pg = g   + bc*4096;
  const u16* pr = Frb + bc*4096;
  const u16* pi = Fib + bc*4096;
  // pass1: T[h][k2] = sum_w P[h][w] IF[k2][w], P = g*F; store T^T (k2-tile = wave)
  #pragma unroll
  for (int mi = 0; mi < 4; ++mi){
    f32x4 a1={0.f,0.f,0.f,0.f}, a2={0.f,0.f,0.f,0.f}, a3={0.f,0.f,0.f,0.f}, a4={0.f,0.f,0.f,0.f};
    #pragma unroll
    for (int ks = 0; ks < 2; ++ks){
      const int ao = (mi*16+lr)*64 + ks*32 + quad*8;
      short8 gv = *(const short8*)(pg + ao);
      short8 apr = mulpk(gv, *(const short8*)(pr + ao));
      short8 api = mulpk(gv, *(const short8*)(pi + ao));
      const int bo = (wave*16+lr)*64 + ks*32 + quad*8;
      short8 br = *(const short8*)(EIr + bo);
      short8 bi = *(const short8*)(EIi + bo);
      a1 = MF(apr, br, a1); a2 = MF(api, bi, a2);
      a3 = MF(apr, bi, a3); a4 = MF(api, br, a4);
    }
    f32x4 tr, ti;
    #pragma unroll
    for (int r = 0; r < 4; ++r){ tr[r] = a1[r]-a2[r]; ti[r] = a3[r]+a4[r]; }
    *(ushort4*)(TTr + (wave*16+lr)*72 + mi*16 + quad*4) = pk4(tr);
    *(ushort4*)(TTi + (wave*16+lr)*72 + mi*16 + quad*4) = pk4(ti);
  }
  __syncthreads();
  // pass2: Y^T[k2][k1] = sum_h T^T[k2][h] IF[k1][h]; out = |Y| + x
  #pragma unroll
  for (int nt = 0; nt < 4; ++nt){
    f32x4 a1={0.f,0.f,0.f,0.f}, a2={0.f,0.f,0.f,0.f}, a3={0.f,0.f,0.f,0.f}, a4={0.f,0.f,0.f,0.f};
    #pragma unroll
    for (int ks = 0; ks < 2; ++ks){
      short8 tr = *(const short8*)(TTr + (wave*16+lr)*72 + ks*32 + quad*8);
      short8 ti = *(const short8*)(TTi + (wave*16+lr)*72 + ks*32 + quad*8);
      const int bo = (nt*16+lr)*64 + ks*32 + quad*8;
      short8 br = *(const short8*)(EIr + bo);
      short8 bi = *(const short8*)(EIi + bo);
      a1 = MF(tr, br, a1); a2 = MF(ti, bi, a2);
      a3 = MF(tr, bi, a3); a4 = MF(ti, br, a4);
    }
    // D[m=k2=wave*16+quad*4+r][n=k1=nt*16+lr]
    const int o = (b*256 + 128 + c)*4096 + (nt*16+lr)*64 + wave*16 + quad*4;
    float xr[4];
    if (f32m) ld4a(xr, (const float*)x + o); else ld4b(xr, (const u16*)x + o);
    float ov[4];
    #pragma unroll
    for (int r = 0; r < 4; ++r){
      float yr = a1[r]-a2[r], yi = a3[r]+a4[r];
      ov[r] = sqrtf(yr*yr + yi*yi) + xr[r];
    }
    st4(out + o, ov);
  }
}

// ===================== 4096-pt IFFT via MFMA, four-step, in place =====================
__global__ __launch_bounds__(256) void k_ifft4096_m(u16* __restrict__ Frb, u16* __restrict__ Fib,
                                                    const float* __restrict__ ws,
                                                    const u16* __restrict__ dft){
  __shared__ __align__(16) u16 A2Tr[64*72], A2Ti[64*72], Cr[64*72], Ci[64*72];
  const int bc = blockIdx.x, t = threadIdx.x;
  const int lane = t & 63, wave = t >> 6;
  const int quad = lane >> 4, lr = lane & 15;
  const u16* EIr = dft + 8192;
  const u16* EIi = dft + 12288;
  const float* twr = ws + TABTW_RE;
  const float* twi = ws + TABTW_IM;
  u16* fr = Frb + bc*4096;
  u16* fi = Fib + bc*4096;
  // stage transpose: A2T[n2][n1] = F[n1][n2]
  for (int i = t; i < 4096; i += 256){
    int n1 = i >> 6, n2 = i & 63;
    A2Tr[n2*72 + n1] = fr[i];
    A2Ti[n2*72 + n1] = fi[i];
  }
  __syncthreads();
  // pass1: T[k1][n2] = sum_n1 IF[k1][n1] A2T[n2][n1]; twiddle -> C[k1][n2]  (k1-tile = wave)
  #pragma unroll
  for (int nt = 0; nt < 4; ++nt){
    f32x4 a1={0.f,0.f,0.f,0.f}, a2={0.f,0.f,0.f,0.f}, a3={0.f,0.f,0.f,0.f}, a4={0.f,0.f,0.f,0.f};
    #pragma unroll
    for (int ks = 0; ks < 2; ++ks){
      const int ao = (wave*16+lr)*64 + ks*32 + quad*8;
      short8 Ar = *(const short8*)(EIr + ao);
      short8 Ai = *(const short8*)(EIi + ao);
      short8 br = *(const short8*)(A2Tr + (nt*16+lr)*72 + ks*32 + quad*8);
      short8 bi = *(const short8*)(A2Ti + (nt*16+lr)*72 + ks*32 + quad*8);
      a1 = MF(Ar, br, a1); a2 = MF(Ai, bi, a2);
      a3 = MF(Ar, bi, a3); a4 = MF(Ai, br, a4);
    }
    // D[m=k1=wave*16+quad*4+r][n=n2=nt*16+lr]
    #pragma unroll
    for (int r = 0; r < 4; ++r){
      const int k1 = wave*16 + quad*4 + r;
      const int n2 = nt*16 + lr;
      const float trv = a1[r]-a2[r], tiv = a3[r]+a4[r];
      const float wr = twr[k1*64 + n2], wi = twi[k1*64 + n2];
      Cr[k1*72 + n2] = f2bu(trv*wr - tiv*wi);
      Ci[k1*72 + n2] = f2bu(trv*wi + tiv*wr);
    }
  }
  __syncthreads();
  // pass2: Z[k1][k2] = sum_n2 C[k1][n2] IF[k2][n2]; store flat = k2*64 + k1  (k1-tile = wave)
  #pragma unroll
  for (int nt = 0; nt < 4; ++nt){
    f32x4 a1={0.f,0.f,0.f,0.f}, a2={0.f,0.f,0.f,0.f}, a3={0.f,0.f,0.f,0.f}, a4={0.f,0.f,0.f,0.f};
    #pragma unroll
    for (int ks = 0; ks < 2; ++ks){
      short8 Ar = *(const short8*)(Cr + (wave*16+lr)*72 + ks*32 + quad*8);
      short8 Ai = *(const short8*)(Ci + (wave*16+lr)*72 + ks*32 + quad*8);
      const int bo = (nt*16+lr)*64 + ks*32 + quad*8;
      short8 br = *(const short8*)(EIr + bo);
      short8 bi = *(const short8*)(EIi + bo);
      a1 = MF(Ar, br, a1); a2 = MF(Ai, bi, a2);
      a3 = MF(Ar, bi, a3); a4 = MF(Ai, br, a4);
    }
    f32x4 zr, zi;
    #pragma unroll
    for (int r = 0; r < 4; ++r){ zr[r] = a1[r]-a2[r]; zi[r] = a3[r]+a4[r]; }
    // D[m=k1=wave*16+quad*4+r][n=k2=nt*16+lr]; flat = k2*64 + k1 -> 4 consecutive k1
    const int flat = (nt*16+lr)*64 + wave*16 + quad*4;
    *(ushort4*)(fr + flat) = pk4(zr);
    *(ushort4*)(fi + flat) = pk4(zi);
  }
}

// ===================== out_f = |M @ Z| + x  (channels 0..127), f32 out =====================
__global__ __launch_bounds__(256) void k_outf(const u16* __restrict__ Zr, const u16* __restrict__ Zi,
                                              const float* __restrict__ wsM, const void* __restrict__ x,
                                              float* __restrict__ out, const int* __restrict__ flg){
  __shared__ float MreT[16][20], MimT[16][20];
  const int gb = blockIdx.x;
  const int bh = gb & 127, nch = gb >> 7;
  const int b = bh >> 3, h = bh & 7;
  const int t = threadIdx.x;
  const int f32m = __builtin_amdgcn_readfirstlane(*flg);
  {
    const int i = t >> 4, j = t & 15;
    MreT[j][i] = wsM[bh*512 + t*2];
    MimT[j][i] = wsM[bh*512 + t*2 + 1];
  }
  __syncthreads();
  const int i0 = (t & 3)*4;
  const int nn = nch*256 + (t >> 2)*4;
  const u16* zr = Zr + (b*128 + h*16)*4096 + nn;
  const u16* zi = Zi + (b*128 + h*16)*4096 + nn;
  float accr[4][4] = {}, acci[4][4] = {};
  #pragma unroll
  for (int j = 0; j < 16; ++j){
    float mr[4], mi[4], vr[4], vi[4];
    ld4a(mr, &MreT[j][i0]);
    ld4a(mi, &MimT[j][i0]);
    ld4b(vr, zr + j*4096);
    ld4b(vi, zi + j*4096);
    #pragma unroll
    for (int i = 0; i < 4; ++i)
      #pragma unroll
      for (int n = 0; n < 4; ++n){
        accr[i][n] += mr[i]*vr[n] - mi[i]*vi[n];
        acci[i][n] += mr[i]*vi[n] + mi[i]*vr[n];
      }
  }
  #pragma unroll
  for (int i = 0; i < 4; ++i){
    const int o = (b*256 + h*16 + i0 + i)*4096 + nn;
    float xr[4];
    if (f32m) ld4a(xr, (const float*)x + o); else ld4b(xr, (const u16*)x + o);
    float ov[4];
    #pragma unroll
    for (int n = 0; n < 4; ++n)
      ov[n] = sqrtf(accr[i][n]*accr[i][n] + acci[i][n]*acci[i][n]) + xr[n];
    st4(out + o, ov);
  }
}

// ===================== launch =====================
extern "C" void kernel_launch(void* const* d_in, const int* in_sizes, int n_in,
                              void* d_out, int out_size, void* d_ws, size_t ws_size,
                              hipStream_t stream) {
  const void* x        = d_in[0];
  const void* conv2_w  = d_in[1];
  const void* conv2_b  = d_in[2];
  const void* bn2_s    = d_in[3];
  const void* bn2_b    = d_in[4];
  const void* temp     = d_in[5];
  const void* w1_w     = d_in[6];
  const void* w1_b     = d_in[7];
  const void* bnw_s    = d_in[8];
  const void* bnw_b    = d_in[9];
  const void* w2_w     = d_in[10];
  const void* w2_b     = d_in[11];
  float* out = (float*)d_out;
  float* wsf = (float*)d_ws;

  if (ws_size < (size_t)(F32_END*4) + 3u*(size_t)BPLANE*2u) return;

  int* flag = (int*)(wsf + FLAG_OFF);
  float* prm = wsf + PRM_OFF;
  u16* wT2 = (u16*)(wsf + WT_OFF);
  u16* dft = (u16*)(wsf + DFT16_OFF);
  u16* wsb = (u16*)(wsf + F32_END);
  u16* Frb = wsb;
  u16* Fib = wsb + BPLANE;
  u16* xt  = wsb;              // aliases Frb+Fib (dead before k_fft2_m writes them)
  u16* Ab  = wsb + 2*BPLANE;   // conv output; later aliased by partials, then g
  u16* g   = Ab;
  float* part = (float*)Ab;    // 8 MB Gram partials (Ab dead after k_fft2_m;
                               // consumed by k_attn2 before k_gate writes g)

  k_detect<<<1, 64, 0, stream>>>((const u16*)x, flag);
  k_tables<<<16, 256, 0, stream>>>(wsf);
  k_dftprep<<<16, 256, 0, stream>>>(dft);
  k_pack<<<1, 256, 0, stream>>>(conv2_b, bn2_s, bn2_b, temp, w1_w, w1_b, bnw_s, bnw_b,
                                w2_w, w2_b, flag, prm);
  k_wprep2<<<1152, 256, 0, stream>>>(conv2_w, wT2, prm, flag);
  k_trans<<<1024, 256, 0, stream>>>(x, xt, flag);
  k_cmm<<<256, 512, 0, stream>>>(xt, wT2, prm, Ab);
  k_fft2_m<<<2048, 256, 0, stream>>>(Ab, Frb, Fib, dft);
  k_attn1<<<2048, 256, 0, stream>>>(Frb, Fib, part);
  k_attn2<<<128, 256, 0, stream>>>(part, prm, wsf + MMAT_OFF);
  k_gate<<<256, 256, 0, stream>>>(Frb, prm, g);
  k_outl_m<<<2048, 256, 0, stream>>>(Frb, Fib, g, x, out, dft, flag);
  k_ifft4096_m<<<2048, 256, 0, stream>>>(Frb, Fib, wsf, dft);
  k_outf<<<2048, 256, 0, stream>>>(Frb, Fib, wsf + MMAT_OFF, x, out, flag);
}

// Round 7
// 426.721 us; speedup vs baseline: 1.0555x; 1.0555x over previous
//
#include <hip/hip_runtime.h>

typedef unsigned short u16;
typedef short short8 __attribute__((ext_vector_type(8)));
typedef float f32x4 __attribute__((ext_vector_type(4)));

#define MF(a,b,c) __builtin_amdgcn_mfma_f32_16x16x32_bf16(a,b,c,0,0,0)

// ---------- bf16 helpers ----------
__device__ __forceinline__ float bu2f(u16 u){
  return __uint_as_float(((unsigned int)u) << 16);
}
__device__ __forceinline__ u16 f2bu(float f){
  unsigned int b = __float_as_uint(f);
  unsigned int r = (b + 0x7FFFu + ((b >> 16) & 1u)) >> 16;  // RNE
  return (u16)r;
}
__device__ __forceinline__ void ld4a(float* d, const float* p){
  float4 v = *(const float4*)p;
  d[0]=v.x; d[1]=v.y; d[2]=v.z; d[3]=v.w;
}
__device__ __forceinline__ void st4(float* p, const float* s){
  *(float4*)p = make_float4(s[0], s[1], s[2], s[3]);
}
__device__ __forceinline__ void ld4b(float* d, const u16* p){
  ushort4 v = *(const ushort4*)p;
  d[0]=bu2f(v.x); d[1]=bu2f(v.y); d[2]=bu2f(v.z); d[3]=bu2f(v.w);
}
__device__ __forceinline__ void st4b(u16* p, const float* s){
  ushort4 v;
  v.x=f2bu(s[0]); v.y=f2bu(s[1]); v.z=f2bu(s[2]); v.w=f2bu(s[3]);
  *(ushort4*)p = v;
}
__device__ __forceinline__ ushort4 pk4(f32x4 v){
  ushort4 u; u.x=f2bu(v[0]); u.y=f2bu(v[1]); u.z=f2bu(v[2]); u.w=f2bu(v[3]); return u;
}
__device__ __forceinline__ short8 mulpk(short8 g, short8 f){
  short8 o;
  #pragma unroll
  for (int e = 0; e < 8; ++e)
    o[e] = (short)f2bu(bu2f((u16)g[e])*bu2f((u16)f[e]));
  return o;
}
// async global->LDS, 16B per lane (dest must be uniform base + lane*16)
__device__ __forceinline__ void gl_lds16(const void* g, void* l){
  __builtin_amdgcn_global_load_lds(
      (const __attribute__((address_space(1))) void*)g,
      (__attribute__((address_space(3))) void*)l, 16, 0, 0);
}

// ---------- workspace layout ----------
#define TABF_RE   0
#define TABF_IM   4096
#define TABIF_RE  8192
#define TABIF_IM  12288
#define TABTW_RE  16384      // exp(+2pi i k1*n2/4096) f32 [k1][n2]
#define TABTW_IM  20480
#define NORMS_OFF 24576
#define MMAT_OFF  26624
#define FLAG_OFF  92160
#define PRM_OFF   92224
#define WT_OFF    94848      // wT2 bf16 conv weights (294912 u16)
#define DFT16_OFF 242304     // bf16 DFT matrices: EFr,EFi,EIr,EIi (4*4096 u16)
#define F32_END   389760
// params sub-offsets:
#define P_CB   0
#define P_BNS  128
#define P_BNB  256
#define P_TEMP 384
#define P_W1   400
#define P_B1   1424
#define P_S1   1432
#define P_BB1  1440
#define P_W2   1456
#define P_B2   2480
// bf16 region:
#define BPLANE    8388608
// x_t aliases Frb+Fib (dead before k_fft2_m writes them); A/g at 2*BPLANE.
// Gram partials (f32, 8 MB) alias the A/g region: A is dead after k_fft2_m,
// and k_gate overwrites g only after k_attn2 consumed the partials.

// ===================== input dtype detection =====================
__global__ void k_detect(const u16* __restrict__ xv, int* __restrict__ flag){
  const int t = threadIdx.x;
  int huge = 0;
  for (int i = 0; i < 16; ++i){
    u16 u = xv[(t*16 + i)*2];
    int e = (u >> 7) & 0xFF;
    huge += (e >= 0xC0) ? 1 : 0;
  }
  #pragma unroll
  for (int off = 32; off > 0; off >>= 1) huge += __shfl_down(huge, off, 64);
  if (t == 0) flag[0] = (huge >= 8) ? 1 : 0;
}

// ===================== tables =====================
__global__ void k_tables(float* ws){
  int idx = blockIdx.x*256 + threadIdx.x;
  int j = idx >> 6, k = idx & 63;
  int jk = j*k;
  float s, c;
  sincospif(-(float)(jk & 63)/32.0f, &s, &c);
  ws[TABF_RE+idx] = c; ws[TABF_IM+idx] = s;
  sincospif((float)(jk & 63)/32.0f, &s, &c);
  ws[TABIF_RE+idx] = c*(1.f/64.f); ws[TABIF_IM+idx] = s*(1.f/64.f);
  sincospif((float)jk/2048.0f, &s, &c);
  ws[TABTW_RE+idx] = c; ws[TABTW_IM+idx] = s;
}

// bf16 DFT matrices (fragment-ready row-major; E is symmetric)
__global__ void k_dftprep(u16* __restrict__ m){
  int idx = blockIdx.x*256 + threadIdx.x;   // 0..4095
  int j = idx >> 6, k = idx & 63;
  int jk = (j*k) & 63;
  float s, c;
  sincospif(-(float)jk/32.0f, &s, &c);
  m[idx]        = f2bu(c);
  m[4096+idx]   = f2bu(s);
  sincospif((float)jk/32.0f, &s, &c);
  m[8192+idx]   = f2bu(c*(1.f/64.f));
  m[12288+idx]  = f2bu(s*(1.f/64.f));
}

// ===================== pack small params -> f32 =====================
__global__ void k_pack(const void* cb, const void* bns, const void* bnb, const void* temp,
                       const void* w1, const void* b1, const void* s1, const void* bb1,
                       const void* w2, const void* b2,
                       const int* __restrict__ flg, float* __restrict__ P){
  const int t = threadIdx.x;
  const int f32 = *flg;
  if (f32){
    for (int i = t; i < 128; i += 256){
      P[P_CB+i]  = ((const float*)cb)[i];
      P[P_BNS+i] = ((const float*)bns)[i];
      P[P_BNB+i] = ((const float*)bnb)[i];
      P[P_B2+i]  = ((const float*)b2)[i];
    }
    for (int i = t; i < 1024; i += 256){
      P[P_W1+i] = ((const float*)w1)[i];
      P[P_W2+i] = ((const float*)w2)[i];
    }
    if (t < 8){
      P[P_TEMP+t] = ((const float*)temp)[t];
      P[P_B1+t]   = ((const float*)b1)[t];
      P[P_S1+t]   = ((const float*)s1)[t];
      P[P_BB1+t]  = ((const float*)bb1)[t];
    }
  } else {
    for (int i = t; i < 128; i += 256){
      P[P_CB+i]  = bu2f(((const u16*)cb)[i]);
      P[P_BNS+i] = bu2f(((const u16*)bns)[i]);
      P[P_BNB+i] = bu2f(((const u16*)bnb)[i]);
      P[P_B2+i]  = bu2f(((const u16*)b2)[i]);
    }
    for (int i = t; i < 1024; i += 256){
      P[P_W1+i] = bu2f(((const u16*)w1)[i]);
      P[P_W2+i] = bu2f(((const u16*)w2)[i]);
    }
    if (t < 8){
      P[P_TEMP+t] = bu2f(((const u16*)temp)[t]);
      P[P_B1+t]   = bu2f(((const u16*)b1)[t]);
      P[P_S1+t]   = bu2f(((const u16*)s1)[t]);
      P[P_BB1+t]  = bu2f(((const u16*)bb1)[t]);
    }
  }
}

// ===================== weight prep for MFMA conv =====================
__global__ void k_wprep2(const void* __restrict__ w, u16* __restrict__ wT2,
                         const float* __restrict__ prm, const int* __restrict__ flg){
  const int f32 = *flg;
  int U = blockIdx.x*256 + threadIdx.x;
  if (U < 294912){
    int j = U & 7;
    int E = U >> 3;
    int n = E & 127;
    int o = (E >> 7) & 3;
    int tc = E >> 9;
    int chunk = tc & 7, tap = tc >> 3;
    int c = chunk*32 + o*8 + j;
    int src = n*2304 + c*9 + tap;
    float v = f32 ? ((const float*)w)[src] : bu2f(((const u16*)w)[src]);
    wT2[U] = f2bu(v * prm[P_BNS + n]);
  }
}

// ===================== x transpose: NCHW -> [b][h][w][c] bf16 =====================
__global__ __launch_bounds__(256) void k_trans(const void* __restrict__ x, u16* __restrict__ xt,
                                               const int* __restrict__ flg){
  __shared__ u16 L[256*66];
  const int t = threadIdx.x;
  const int b = blockIdx.x >> 6, h = blockIdx.x & 63;
  const int f32m = __builtin_amdgcn_readfirstlane(*flg);
  if (f32m){
    const float* xf = (const float*)x;
    for (int i = t; i < 16384; i += 256){
      int c = i >> 6, w = i & 63;
      L[c*66 + w] = f2bu(xf[((b*256 + c)*64 + h)*64 + w]);
    }
  } else {
    const u16* xb = (const u16*)x;
    for (int i = t; i < 16384; i += 256){
      int c = i >> 6, w = i & 63;
      L[c*66 + w] = xb[((b*256 + c)*64 + h)*64 + w];
    }
  }
  __syncthreads();
  u16* dst = xt + ((b*64 + h)*64)*256;
  for (int j = t; j < 16384; j += 256){
    int w = j >> 8, c = j & 255;
    dst[w*256 + c] = L[c*66 + w];
  }
}

// ===================== MFMA implicit-GEMM conv + BN + ReLU =====================
// M-split for occupancy WITHOUT narrowing N (the r2/r4/r6 lesson: acc[*][8] keeps
// MFMA:A-load = 8:1 and a register-rich ~168-VGPR schedule; acc[*][4] collapses it).
// Block = 2 h-rows; wave = (wrow 0..1, whalf 0..1): 32 w-pos x all 128 channels
// per wave -> acc[2][8]. Grid = 16 bb x 32 row-pairs = 512 blocks.
// Single-buffer 64 KB weight LDS (r1's 2-barrier/tap, staged via zero-VGPR gl_lds)
// -> 2 blocks/CU = 2 waves/SIMD; cross-block overlap (m114) hides barrier drains.
// XCD decode keeps both images of an XCD L2-resident (r4/r5-proven, FETCH ~32 MB).
__global__ __launch_bounds__(256) void k_cmm(const u16* __restrict__ xt, const u16* __restrict__ wT2,
                                             const float* __restrict__ prm, u16* __restrict__ A){
  __shared__ __align__(16) uint4 sm4[4096];   // 64 KB single weight buffer
  const int t = threadIdx.x;
  const int blk = blockIdx.x;
  const int bb = (blk & 7) + 8*(blk >> 8);    // xcd = blk&7; bb in {xcd, xcd+8}
  const int mt2 = (blk >> 3) & 31;            // 2-row tile index
  const int lane = t & 63, wave = t >> 6;
  const int wrow = wave >> 1, whalf = wave & 1;
  const int quad = lane >> 4, lr = lane & 15;

  f32x4 acc[2][8];
  #pragma unroll
  for (int mi = 0; mi < 2; ++mi)
    #pragma unroll
    for (int nt = 0; nt < 8; ++nt)
      acc[mi][nt] = (f32x4){0.f,0.f,0.f,0.f};

  const short8 zz = {0,0,0,0,0,0,0,0};

  for (int tap = 0; tap < 9; ++tap){
    const int ky = tap/3, kx = tap - ky*3;
    __syncthreads();   // all waves done reading previous tap's buffer
    {
      const uint4* src = (const uint4*)(wT2 + tap*32768);
      #pragma unroll
      for (int i = 0; i < 16; ++i) gl_lds16(&src[t + 256*i], &sm4[t + 256*i]);
    }
    __syncthreads();   // vmcnt(0) drain + barrier

    const u16* smB = (const u16*)sm4;
    const int hg = mt2*2 + wrow + 3*ky - 3;
    const bool hok = ((unsigned)hg < 64u);
    const u16* abase = xt + ((bb*64 + hg)*64)*256 + quad*8;

    for (int chunk = 0; chunk < 8; ++chunk){
      short8 av[2];
      #pragma unroll
      for (int mi = 0; mi < 2; ++mi){
        const int wg = whalf*32 + mi*16 + lr + 3*kx - 3;
        short8 v = zz;
        if (hok && ((unsigned)wg < 64u))
          v = *(const short8*)(abase + wg*256 + chunk*32);
        av[mi] = v;
      }
      short8 bv[8];
      #pragma unroll
      for (int nt = 0; nt < 8; ++nt)
        bv[nt] = *(const short8*)(smB + (chunk*512 + quad*128 + nt*16 + lr)*8);
      #pragma unroll
      for (int mi = 0; mi < 2; ++mi)
        #pragma unroll
        for (int nt = 0; nt < 8; ++nt)
          acc[mi][nt] = MF(av[mi], bv[nt], acc[mi][nt]);
    }
  }

  // epilogue: transpose through LDS (sm4 reused: 16x133 f32 = 8.5 KB),
  // 8 rounds of 16 channels over M=128 block pixels.
  float* C = (float*)sm4;
  u16* outb = A + (bb*128)*4096 + mt2*128;
  __syncthreads();
  for (int nt = 0; nt < 8; ++nt){
    #pragma unroll
    for (int mi = 0; mi < 2; ++mi)
      #pragma unroll
      for (int r = 0; r < 4; ++r){
        const int m = wrow*64 + whalf*32 + mi*16 + quad*4 + r;
        C[lr*133 + m] = acc[mi][nt][r];
      }
    __syncthreads();
    #pragma unroll
    for (int i = 0; i < 8; ++i){
      const int idx = i*256 + t;
      const int dd = idx >> 7, m = idx & 127;
      const int d = nt*16 + dd;
      const float bi = prm[P_CB + d]*prm[P_BNS + d] + prm[P_BNB + d];
      const float v = fmaxf(C[dd*133 + m] + bi, 0.f);
      outb[d*4096 + m] = f2bu(v);
    }
    __syncthreads();
  }
}

// ===================== fft2 via MFMA: F = E*img*E per (b,c) =====================
__global__ __launch_bounds__(256) void k_fft2_m(const u16* __restrict__ A, u16* __restrict__ Frb,
                                                u16* __restrict__ Fib, const u16* __restrict__ dft){
  __shared__ __align__(16) u16 TTr[64*72], TTi[64*72];
  const int bc = blockIdx.x, t = threadIdx.x;
  const int lane = t & 63, wave = t >> 6;
  const int quad = lane >> 4, lr = lane & 15;
  const u16* EFr = dft;
  const u16* EFi = dft + 4096;
  const u16* img = A + bc*4096;
  // pass1: T[h][k2] = sum_w img[h][w] E[k2][w]; store T^T[k2][h] (k2-tile = wave)
  #pragma unroll
  for (int mi = 0; mi < 4; ++mi){
    f32x4 ar = {0.f,0.f,0.f,0.f}, ai = {0.f,0.f,0.f,0.f};
    #pragma unroll
    for (int ks = 0; ks < 2; ++ks){
      short8 av = *(const short8*)(img + (mi*16+lr)*64 + ks*32 + quad*8);
      short8 br = *(const short8*)(EFr + (wave*16+lr)*64 + ks*32 + quad*8);
      short8 bi = *(const short8*)(EFi + (wave*16+lr)*64 + ks*32 + quad*8);
      ar = MF(av, br, ar); ai = MF(av, bi, ai);
    }
    // D[m=h=mi*16+quad*4+r][n=k2=wave*16+lr]
    *(ushort4*)(TTr + (wave*16+lr)*72 + mi*16 + quad*4) = pk4(ar);
    *(ushort4*)(TTi + (wave*16+lr)*72 + mi*16 + quad*4) = pk4(ai);
  }
  __syncthreads();
  // pass2: F^T[k2][k1] = sum_h T^T[k2][h] E[k1][h]  (k2-tile = wave)
  #pragma unroll
  for (int nt = 0; nt < 4; ++nt){
    f32x4 a1={0.f,0.f,0.f,0.f}, a2={0.f,0.f,0.f,0.f}, a3={0.f,0.f,0.f,0.f}, a4={0.f,0.f,0.f,0.f};
    #pragma unroll
    for (int ks = 0; ks < 2; ++ks){
      short8 tr = *(const short8*)(TTr + (wave*16+lr)*72 + ks*32 + quad*8);
      short8 ti = *(const short8*)(TTi + (wave*16+lr)*72 + ks*32 + quad*8);
      short8 br = *(const short8*)(EFr + (nt*16+lr)*64 + ks*32 + quad*8);
      short8 bi = *(const short8*)(EFi + (nt*16+lr)*64 + ks*32 + quad*8);
      a1 = MF(tr, br, a1); a2 = MF(ti, bi, a2);
      a3 = MF(tr, bi, a3); a4 = MF(ti, br, a4);
    }
    f32x4 fr, fi;
    #pragma unroll
    for (int r = 0; r < 4; ++r){ fr[r] = a1[r]-a2[r]; fi[r] = a3[r]+a4[r]; }
    // D[m=k2=wave*16+quad*4+r][n=k1=nt*16+lr]; flat = k1*64 + k2
    const int flat = (nt*16+lr)*64 + wave*16 + quad*4;
    *(ushort4*)(Frb + bc*4096 + flat) = pk4(fr);
    *(ushort4*)(Fib + bc*4096 + flat) = pk4(fi);
  }
}

// ===================== attention phase 1: split-K MFMA Gram partials =====================
// grid = 128 (b,h) * 16 n-chunks; each wave owns 64 columns (2 K-steps).
// Partials p1=Ar*Ar^T, p2=Ai*Ai^T, p3=Ar*Ai^T, p4=Ai*Ar^T stored raw so that
// phase 2 recovers gr=p1-p2, gi=p3+p4 AND norms^2[i]=(p1+p2)[i][i] (k_norms is gone).
__global__ __launch_bounds__(256) void k_attn1(const u16* __restrict__ Frb,
                                               const u16* __restrict__ Fib,
                                               float* __restrict__ part){
  __shared__ float R[4][4][256];   // [wave][q][m*16+n]
  const int blk = blockIdx.x;
  const int bh = blk >> 4, chunk = blk & 15;
  const int t = threadIdx.x, lane = t & 63, wave = t >> 6;
  const int quad = lane >> 4, lr = lane & 15;
  const u16* fr = Frb + bh*65536;
  const u16* fi = Fib + bh*65536;
  const int c0 = chunk*256 + wave*64;
  f32x4 a1={0.f,0.f,0.f,0.f}, a2={0.f,0.f,0.f,0.f}, a3={0.f,0.f,0.f,0.f}, a4={0.f,0.f,0.f,0.f};
  #pragma unroll
  for (int ks = 0; ks < 2; ++ks){
    const int off = lr*4096 + c0 + ks*32 + quad*8;
    short8 ar = *(const short8*)(fr + off);
    short8 ai = *(const short8*)(fi + off);
    a1 = MF(ar, ar, a1); a2 = MF(ai, ai, a2);
    a3 = MF(ar, ai, a3); a4 = MF(ai, ar, a4);
  }
  // D[m=quad*4+r][n=lr]
  #pragma unroll
  for (int r = 0; r < 4; ++r){
    const int mn = (quad*4 + r)*16 + lr;
    R[wave][0][mn] = a1[r];
    R[wave][1][mn] = a2[r];
    R[wave][2][mn] = a3[r];
    R[wave][3][mn] = a4[r];
  }
  __syncthreads();
  float* dst = part + blk*1024;
  #pragma unroll
  for (int q = 0; q < 4; ++q)
    dst[q*256 + t] = R[0][q][t] + R[1][q][t] + R[2][q][t] + R[3][q][t];
}

// ===================== attention phase 2: reduce + norms + dual softmax + c-axis ifft fold ===
__global__ __launch_bounds__(256) void k_attn2(const float* __restrict__ part,
                                               const float* __restrict__ prm,
                                               float* __restrict__ wsM){
  __shared__ float AR[16][17], AI[16][17], NR[16];
  const int bh = blockIdx.x;
  const int h = bh & 7;
  const int t = threadIdx.x;
  const float* p = part + bh*16384;
  float s1=0.f, s2=0.f, s3=0.f, s4=0.f;
  #pragma unroll
  for (int ch = 0; ch < 16; ++ch){
    s1 += p[ch*1024 +       t];
    s2 += p[ch*1024 + 256 + t];
    s3 += p[ch*1024 + 512 + t];
    s4 += p[ch*1024 + 768 + t];
  }
  const int m = t >> 4, n = t & 15;
  if (m == n) NR[m] = fmaxf(sqrtf(fmaxf(s1 + s2, 0.f)), 1e-12f);
  __syncthreads();
  const float sc = prm[P_TEMP + h] / (NR[m]*NR[n]);
  AR[m][n] = (s1 - s2)*sc;
  AI[m][n] = (s3 + s4)*sc;
  __syncthreads();
  if (t < 32){
    float* row = (t < 16) ? AR[t & 15] : AI[t & 15];
    float mx = row[0];
    for (int j2 = 1; j2 < 16; ++j2) mx = fmaxf(mx, row[j2]);
    float s = 0.f, e[16];
    for (int j2 = 0; j2 < 16; ++j2){ e[j2] = expf(row[j2] - mx); s += e[j2]; }
    float inv = 1.f/s;
    for (int j2 = 0; j2 < 16; ++j2) row[j2] = e[j2]*inv;
  }
  __syncthreads();
  {
    const int mi = t >> 4, mj = t & 15;
    float mr = 0.f, mim = 0.f;
    #pragma unroll
    for (int pp = 0; pp < 16; ++pp){
      float sv, cv;
      sincospif((float)((mi*pp) & 15)/8.0f, &sv, &cv);
      const float arv = AR[pp][mj], aiv = AI[pp][mj];
      mr  += cv*arv - sv*aiv;
      mim += cv*aiv + sv*arv;
    }
    wsM[bh*512 + t*2]     = mr*(1.f/16.f);
    wsM[bh*512 + t*2 + 1] = mim*(1.f/16.f);
  }
}

// ===================== gating MLP -> g plane (bf16) =====================
__global__ __launch_bounds__(256) void k_gate(const u16* __restrict__ Frb,
                                              const float* __restrict__ prm,
                                              u16* __restrict__ g){
  __shared__ float W1T[128][8];
  __shared__ float W2[128][8];
  __shared__ float B1v[8], S1v[8], BB1v[8];
  __shared__ float B2v[128];
  const int t = threadIdx.x;
  for (int i = t; i < 1024; i += 256){
    W1T[i & 127][i >> 7] = prm[P_W1 + i];
    W2[i >> 3][i & 7]    = prm[P_W2 + i];
  }
  if (t < 8){ B1v[t] = prm[P_B1+t]; S1v[t] = prm[P_S1+t]; BB1v[t] = prm[P_BB1+t]; }
  if (t < 128) B2v[t] = prm[P_B2+t];
  __syncthreads();
  const int pix = blockIdx.x*256 + t;
  const int b = pix >> 12, n = pix & 4095;
  const u16* fr = Frb + b*128*4096 + n;
  float q[8] = {};
  for (int c = 0; c < 128; ++c){
    const float v = bu2f(fr[c*4096]);
    float wa[4], wb[4];
    ld4a(wa, &W1T[c][0]); ld4a(wb, &W1T[c][4]);
    #pragma unroll
    for (int k = 0; k < 4; ++k){ q[k] = fmaf(wa[k], v, q[k]); q[4+k] = fmaf(wb[k], v, q[4+k]); }
  }
  float qa[8];
  #pragma unroll
  for (int k = 0; k < 8; ++k)
    qa[k] = fmaxf(fmaf(q[k] + B1v[k], S1v[k], BB1v[k]), 0.f);
  u16* grow = g + b*128*4096 + n;
  for (int c = 0; c < 128; ++c){
    float wa[4], wb[4];
    ld4a(wa, &W2[c][0]); ld4a(wb, &W2[c][4]);
    float acc = B2v[c];
    #pragma unroll
    for (int k = 0; k < 4; ++k) acc += wa[k]*qa[k] + wb[k]*qa[4+k];
    grow[c*4096] = f2bu(1.f/(1.f + expf(-acc)));
  }
}

// ===================== out_l = |ifft2(g*F)| + x via MFMA (channels 128..255) =====================
__global__ __launch_bounds__(256) void k_outl_m(const u16* __restrict__ Frb, const u16* __restrict__ Fib,
                                                const u16* __restrict__ g, const void* __restrict__ x,
                                                float* __restrict__ out, const u16* __restrict__ dft,
                                                const int* __restrict__ flg){
  __shared__ __align__(16) u16 TTr[64*72], TTi[64*72];
  const int bc = blockIdx.x, t = threadIdx.x;
  const int b = bc >> 7, c = bc & 127;
  const int lane = t & 63, wave = t >> 6;
  const int quad = lane >> 4, lr = lane & 15;
  const int f32m = __builtin_amdgcn_readfirstlane(*flg);
  const u16* EIr = dft + 8192;
  const u16* EIi = dft + 12288;
  const u16* pg = g   + bc*4096;
  const u16* pr = Frb + bc*4096;
  const u16* pi = Fib + bc*4096;
  // pass1: T[h][k2] = sum_w P[h][w] IF[k2][w], P = g*F; store T^T (k2-tile = wave)
  #pragma unroll
  for (int mi = 0; mi < 4; ++mi){
    f32x4 a1={0.f,0.f,0.f,0.f}, a2={0.f,0.f,0.f,0.f}, a3={0.f,0.f,0.f,0.f}, a4={0.f,0.f,0.f,0.f};
    #pragma unroll
    for (int ks = 0; ks < 2; ++ks){
      const int ao = (mi*16+lr)*64 + ks*32 + quad*8;
      short8 gv = *(const short8*)(pg + ao);
      short8 apr = mulpk(gv, *(const short8*)(pr + ao));
      short8 api = mulpk(gv, *(const short8*)(pi + ao));
      const int bo = (wave*16+lr)*64 + ks*32 + quad*8;
      short8 br = *(const short8*)(EIr + bo);
      short8 bi = *(const short8*)(EIi + bo);
      a1 = MF(apr, br, a1); a2 = MF(api, bi, a2);
      a3 = MF(apr, bi, a3); a4 = MF(api, br, a4);
    }
    f32x4 tr, ti;
    #pragma unroll
    for (int r = 0; r < 4; ++r){ tr[r] = a1[r]-a2[r]; ti[r] = a3[r]+a4[r]; }
    *(ushort4*)(TTr + (wave*16+lr)*72 + mi*16 + quad*4) = pk4(tr);
    *(ushort4*)(TTi + (wave*16+lr)*72 + mi*16 + quad*4) = pk4(ti);
  }
  __syncthreads();
  // pass2: Y^T[k2][k1] = sum_h T^T[k2][h] IF[k1][h]; out = |Y| + x
  #pragma unroll
  for (int nt = 0; nt < 4; ++nt){
    f32x4 a1={0.f,0.f,0.f,0.f}, a2={0.f,0.f,0.f,0.f}, a3={0.f,0.f,0.f,0.f}, a4={0.f,0.f,0.f,0.f};
    #pragma unroll
    for (int ks = 0; ks < 2; ++ks){
      short8 tr = *(const short8*)(TTr + (wave*16+lr)*72 + ks*32 + quad*8);
      short8 ti = *(const short8*)(TTi + (wave*16+lr)*72 + ks*32 + quad*8);
      const int bo = (nt*16+lr)*64 + ks*32 + quad*8;
      short8 br = *(const short8*)(EIr + bo);
      short8 bi = *(const short8*)(EIi + bo);
      a1 = MF(tr, br, a1); a2 = MF(ti, bi, a2);
      a3 = MF(tr, bi, a3); a4 = MF(ti, br, a4);
    }
    // D[m=k2=wave*16+quad*4+r][n=k1=nt*16+lr]
    const int o = (b*256 + 128 + c)*4096 + (nt*16+lr)*64 + wave*16 + quad*4;
    float xr[4];
    if (f32m) ld4a(xr, (const float*)x + o); else ld4b(xr, (const u16*)x + o);
    float ov[4];
    #pragma unroll
    for (int r = 0; r < 4; ++r){
      float yr = a1[r]-a2[r], yi = a3[r]+a4[r];
      ov[r] = sqrtf(yr*yr + yi*yi) + xr[r];
    }
    st4(out + o, ov);
  }
}

// ===================== 4096-pt IFFT via MFMA, four-step, in place =====================
__global__ __launch_bounds__(256) void k_ifft4096_m(u16* __restrict__ Frb, u16* __restrict__ Fib,
                                                    const float* __restrict__ ws,
                                                    const u16* __restrict__ dft){
  __shared__ __align__(16) u16 A2Tr[64*72], A2Ti[64*72], Cr[64*72], Ci[64*72];
  const int bc = blockIdx.x, t = threadIdx.x;
  const int lane = t & 63, wave = t >> 6;
  const int quad = lane >> 4, lr = lane & 15;
  const u16* EIr = dft + 8192;
  const u16* EIi = dft + 12288;
  const float* twr = ws + TABTW_RE;
  const float* twi = ws + TABTW_IM;
  u16* fr = Frb + bc*4096;
  u16* fi = Fib + bc*4096;
  // stage transpose: A2T[n2][n1] = F[n1][n2]
  for (int i = t; i < 4096; i += 256){
    int n1 = i >> 6, n2 = i & 63;
    A2Tr[n2*72 + n1] = fr[i];
    A2Ti[n2*72 + n1] = fi[i];
  }
  __syncthreads();
  // pass1: T[k1][n2] = sum_n1 IF[k1][n1] A2T[n2][n1]; twiddle -> C[k1][n2]  (k1-tile = wave)
  #pragma unroll
  for (int nt = 0; nt < 4; ++nt){
    f32x4 a1={0.f,0.f,0.f,0.f}, a2={0.f,0.f,0.f,0.f}, a3={0.f,0.f,0.f,0.f}, a4={0.f,0.f,0.f,0.f};
    #pragma unroll
    for (int ks = 0; ks < 2; ++ks){
      const int ao = (wave*16+lr)*64 + ks*32 + quad*8;
      short8 Ar = *(const short8*)(EIr + ao);
      short8 Ai = *(const short8*)(EIi + ao);
      short8 br = *(const short8*)(A2Tr + (nt*16+lr)*72 + ks*32 + quad*8);
      short8 bi = *(const short8*)(A2Ti + (nt*16+lr)*72 + ks*32 + quad*8);
      a1 = MF(Ar, br, a1); a2 = MF(Ai, bi, a2);
      a3 = MF(Ar, bi, a3); a4 = MF(Ai, br, a4);
    }
    // D[m=k1=wave*16+quad*4+r][n=n2=nt*16+lr]
    #pragma unroll
    for (int r = 0; r < 4; ++r){
      const int k1 = wave*16 + quad*4 + r;
      const int n2 = nt*16 + lr;
      const float trv = a1[r]-a2[r], tiv = a3[r]+a4[r];
      const float wr = twr[k1*64 + n2], wi = twi[k1*64 + n2];
      Cr[k1*72 + n2] = f2bu(trv*wr - tiv*wi);
      Ci[k1*72 + n2] = f2bu(trv*wi + tiv*wr);
    }
  }
  __syncthreads();
  // pass2: Z[k1][k2] = sum_n2 C[k1][n2] IF[k2][n2]; store flat = k2*64 + k1  (k1-tile = wave)
  #pragma unroll
  for (int nt = 0; nt < 4; ++nt){
    f32x4 a1={0.f,0.f,0.f,0.f}, a2={0.f,0.f,0.f,0.f}, a3={0.f,0.f,0.f,0.f}, a4={0.f,0.f,0.f,0.f};
    #pragma unroll
    for (int ks = 0; ks < 2; ++ks){
      short8 Ar = *(const short8*)(Cr + (wave*16+lr)*72 + ks*32 + quad*8);
      short8 Ai = *(const short8*)(Ci + (wave*16+lr)*72 + ks*32 + quad*8);
      const int bo = (nt*16+lr)*64 + ks*32 + quad*8;
      short8 br = *(const short8*)(EIr + bo);
      short8 bi = *(const short8*)(EIi + bo);
      a1 = MF(Ar, br, a1); a2 = MF(Ai, bi, a2);
      a3 = MF(Ar, bi, a3); a4 = MF(Ai, br, a4);
    }
    f32x4 zr, zi;
    #pragma unroll
    for (int r = 0; r < 4; ++r){ zr[r] = a1[r]-a2[r]; zi[r] = a3[r]+a4[r]; }
    // D[m=k1=wave*16+quad*4+r][n=k2=nt*16+lr]; flat = k2*64 + k1 -> 4 consecutive k1
    const int flat = (nt*16+lr)*64 + wave*16 + quad*4;
    *(ushort4*)(fr + flat) = pk4(zr);
    *(ushort4*)(fi + flat) = pk4(zi);
  }
}

// ===================== out_f = |M @ Z| + x  (channels 0..127), f32 out =====================
__global__ __launch_bounds__(256) void k_outf(const u16* __restrict__ Zr, const u16* __restrict__ Zi,
                                              const float* __restrict__ wsM, const void* __restrict__ x,
                                              float* __restrict__ out, const int* __restrict__ flg){
  __shared__ float MreT[16][20], MimT[16][20];
  const int gb = blockIdx.x;
  const int bh = gb & 127, nch = gb >> 7;
  const int b = bh >> 3, h = bh & 7;
  const int t = threadIdx.x;
  const int f32m = __builtin_amdgcn_readfirstlane(*flg);
  {
    const int i = t >> 4, j = t & 15;
    MreT[j][i] = wsM[bh*512 + t*2];
    MimT[j][i] = wsM[bh*512 + t*2 + 1];
  }
  __syncthreads();
  const int i0 = (t & 3)*4;
  const int nn = nch*256 + (t >> 2)*4;
  const u16* zr = Zr + (b*128 + h*16)*4096 + nn;
  const u16* zi = Zi + (b*128 + h*16)*4096 + nn;
  float accr[4][4] = {}, acci[4][4] = {};
  #pragma unroll
  for (int j = 0; j < 16; ++j){
    float mr[4], mi[4], vr[4], vi[4];
    ld4a(mr, &MreT[j][i0]);
    ld4a(mi, &MimT[j][i0]);
    ld4b(vr, zr + j*4096);
    ld4b(vi, zi + j*4096);
    #pragma unroll
    for (int i = 0; i < 4; ++i)
      #pragma unroll
      for (int n = 0; n < 4; ++n){
        accr[i][n] += mr[i]*vr[n] - mi[i]*vi[n];
        acci[i][n] += mr[i]*vi[n] + mi[i]*vr[n];
      }
  }
  #pragma unroll
  for (int i = 0; i < 4; ++i){
    const int o = (b*256 + h*16 + i0 + i)*4096 + nn;
    float xr[4];
    if (f32m) ld4a(xr, (const float*)x + o); else ld4b(xr, (const u16*)x + o);
    float ov[4];
    #pragma unroll
    for (int n = 0; n < 4; ++n)
      ov[n] = sqrtf(accr[i][n]*accr[i][n] + acci[i][n]*acci[i][n]) + xr[n];
    st4(out + o, ov);
  }
}

// ===================== launch =====================
extern "C" void kernel_launch(void* const* d_in, const int* in_sizes, int n_in,
                              void* d_out, int out_size, void* d_ws, size_t ws_size,
                              hipStream_t stream) {
  const void* x        = d_in[0];
  const void* conv2_w  = d_in[1];
  const void* conv2_b  = d_in[2];
  const void* bn2_s    = d_in[3];
  const void* bn2_b    = d_in[4];
  const void* temp     = d_in[5];
  const void* w1_w     = d_in[6];
  const void* w1_b     = d_in[7];
  const void* bnw_s    = d_in[8];
  const void* bnw_b    = d_in[9];
  const void* w2_w     = d_in[10];
  const void* w2_b     = d_in[11];
  float* out = (float*)d_out;
  float* wsf = (float*)d_ws;

  if (ws_size < (size_t)(F32_END*4) + 3u*(size_t)BPLANE*2u) return;

  int* flag = (int*)(wsf + FLAG_OFF);
  float* prm = wsf + PRM_OFF;
  u16* wT2 = (u16*)(wsf + WT_OFF);
  u16* dft = (u16*)(wsf + DFT16_OFF);
  u16* wsb = (u16*)(wsf + F32_END);
  u16* Frb = wsb;
  u16* Fib = wsb + BPLANE;
  u16* xt  = wsb;              // aliases Frb+Fib (dead before k_fft2_m writes them)
  u16* Ab  = wsb + 2*BPLANE;   // conv output; later aliased by partials, then g
  u16* g   = Ab;
  float* part = (float*)Ab;    // 8 MB Gram partials (Ab dead after k_fft2_m;
                               // consumed by k_attn2 before k_gate writes g)

  k_detect<<<1, 64, 0, stream>>>((const u16*)x, flag);
  k_tables<<<16, 256, 0, stream>>>(wsf);
  k_dftprep<<<16, 256, 0, stream>>>(dft);
  k_pack<<<1, 256, 0, stream>>>(conv2_b, bn2_s, bn2_b, temp, w1_w, w1_b, bnw_s, bnw_b,
                                w2_w, w2_b, flag, prm);
  k_wprep2<<<1152, 256, 0, stream>>>(conv2_w, wT2, prm, flag);
  k_trans<<<1024, 256, 0, stream>>>(x, xt, flag);
  k_cmm<<<512, 256, 0, stream>>>(xt, wT2, prm, Ab);
  k_fft2_m<<<2048, 256, 0, stream>>>(Ab, Frb, Fib, dft);
  k_attn1<<<2048, 256, 0, stream>>>(Frb, Fib, part);
  k_attn2<<<128, 256, 0, stream>>>(part, prm, wsf + MMAT_OFF);
  k_gate<<<256, 256, 0, stream>>>(Frb, prm, g);
  k_outl_m<<<2048, 256, 0, stream>>>(Frb, Fib, g, x, out, dft, flag);
  k_ifft4096_m<<<2048, 256, 0, stream>>>(Frb, Fib, wsf, dft);
  k_outf<<<2048, 256, 0, stream>>>(Frb, Fib, wsf + MMAT_OFF, x, out, flag);
}

// Round 9
// 413.356 us; speedup vs baseline: 1.0896x; 1.0323x over previous
//
#include <hip/hip_runtime.h>

typedef unsigned short u16;
typedef short short8 __attribute__((ext_vector_type(8)));
typedef float f32x4 __attribute__((ext_vector_type(4)));

#define MF(a,b,c) __builtin_amdgcn_mfma_f32_16x16x32_bf16(a,b,c,0,0,0)

// ---------- bf16 helpers ----------
__device__ __forceinline__ float bu2f(u16 u){
  return __uint_as_float(((unsigned int)u) << 16);
}
__device__ __forceinline__ u16 f2bu(float f){
  unsigned int b = __float_as_uint(f);
  unsigned int r = (b + 0x7FFFu + ((b >> 16) & 1u)) >> 16;  // RNE
  return (u16)r;
}
__device__ __forceinline__ void ld4a(float* d, const float* p){
  float4 v = *(const float4*)p;
  d[0]=v.x; d[1]=v.y; d[2]=v.z; d[3]=v.w;
}
__device__ __forceinline__ void st4(float* p, const float* s){
  *(float4*)p = make_float4(s[0], s[1], s[2], s[3]);
}
__device__ __forceinline__ void ld4b(float* d, const u16* p){
  ushort4 v = *(const ushort4*)p;
  d[0]=bu2f(v.x); d[1]=bu2f(v.y); d[2]=bu2f(v.z); d[3]=bu2f(v.w);
}
__device__ __forceinline__ void st4b(u16* p, const float* s){
  ushort4 v;
  v.x=f2bu(s[0]); v.y=f2bu(s[1]); v.z=f2bu(s[2]); v.w=f2bu(s[3]);
  *(ushort4*)p = v;
}
__device__ __forceinline__ ushort4 pk4(f32x4 v){
  ushort4 u; u.x=f2bu(v[0]); u.y=f2bu(v[1]); u.z=f2bu(v[2]); u.w=f2bu(v[3]); return u;
}
__device__ __forceinline__ short8 mulpk(short8 g, short8 f){
  short8 o;
  #pragma unroll
  for (int e = 0; e < 8; ++e)
    o[e] = (short)f2bu(bu2f((u16)g[e])*bu2f((u16)f[e]));
  return o;
}
// async global->LDS, 16B per lane (dest must be uniform base + lane*16)
__device__ __forceinline__ void gl_lds16(const void* g, void* l){
  __builtin_amdgcn_global_load_lds(
      (const __attribute__((address_space(1))) void*)g,
      (__attribute__((address_space(3))) void*)l, 16, 0, 0);
}

// ---------- workspace layout ----------
#define TABF_RE   0
#define TABF_IM   4096
#define TABIF_RE  8192
#define TABIF_IM  12288
#define TABTW_RE  16384      // exp(+2pi i k1*n2/4096) f32 [k1][n2]
#define TABTW_IM  20480
#define NORMS_OFF 24576
#define MMAT_OFF  26624
#define FLAG_OFF  92160
#define PRM_OFF   92224
#define WT_OFF    94848      // wT2 bf16 conv weights (294912 u16)
#define DFT16_OFF 242304     // bf16 DFT matrices: EFr,EFi,EIr,EIi (4*4096 u16)
#define F32_END   389760
// params sub-offsets:
#define P_CB   0
#define P_BNS  128
#define P_BNB  256
#define P_TEMP 384
#define P_W1   400
#define P_B1   1424
#define P_S1   1432
#define P_BB1  1440
#define P_W2   1456
#define P_B2   2480
// bf16 region:
#define BPLANE    8388608
// x_t aliases Frb+Fib (dead before k_fft2_m writes them); A/g at 2*BPLANE.
// Gram partials (f32, 8 MB) alias the A/g region: A is dead after k_fft2_m,
// and k_gate overwrites g only after k_attn2 consumed the partials.

// ===================== input dtype detection =====================
__global__ void k_detect(const u16* __restrict__ xv, int* __restrict__ flag){
  const int t = threadIdx.x;
  int huge = 0;
  for (int i = 0; i < 16; ++i){
    u16 u = xv[(t*16 + i)*2];
    int e = (u >> 7) & 0xFF;
    huge += (e >= 0xC0) ? 1 : 0;
  }
  #pragma unroll
  for (int off = 32; off > 0; off >>= 1) huge += __shfl_down(huge, off, 64);
  if (t == 0) flag[0] = (huge >= 8) ? 1 : 0;
}

// ===================== tables =====================
__global__ void k_tables(float* ws){
  int idx = blockIdx.x*256 + threadIdx.x;
  int j = idx >> 6, k = idx & 63;
  int jk = j*k;
  float s, c;
  sincospif(-(float)(jk & 63)/32.0f, &s, &c);
  ws[TABF_RE+idx] = c; ws[TABF_IM+idx] = s;
  sincospif((float)(jk & 63)/32.0f, &s, &c);
  ws[TABIF_RE+idx] = c*(1.f/64.f); ws[TABIF_IM+idx] = s*(1.f/64.f);
  sincospif((float)jk/2048.0f, &s, &c);
  ws[TABTW_RE+idx] = c; ws[TABTW_IM+idx] = s;
}

// bf16 DFT matrices (fragment-ready row-major; E is symmetric)
__global__ void k_dftprep(u16* __restrict__ m){
  int idx = blockIdx.x*256 + threadIdx.x;   // 0..4095
  int j = idx >> 6, k = idx & 63;
  int jk = (j*k) & 63;
  float s, c;
  sincospif(-(float)jk/32.0f, &s, &c);
  m[idx]        = f2bu(c);
  m[4096+idx]   = f2bu(s);
  sincospif((float)jk/32.0f, &s, &c);
  m[8192+idx]   = f2bu(c*(1.f/64.f));
  m[12288+idx]  = f2bu(s*(1.f/64.f));
}

// ===================== pack small params -> f32 =====================
__global__ void k_pack(const void* cb, const void* bns, const void* bnb, const void* temp,
                       const void* w1, const void* b1, const void* s1, const void* bb1,
                       const void* w2, const void* b2,
                       const int* __restrict__ flg, float* __restrict__ P){
  const int t = threadIdx.x;
  const int f32 = *flg;
  if (f32){
    for (int i = t; i < 128; i += 256){
      P[P_CB+i]  = ((const float*)cb)[i];
      P[P_BNS+i] = ((const float*)bns)[i];
      P[P_BNB+i] = ((const float*)bnb)[i];
      P[P_B2+i]  = ((const float*)b2)[i];
    }
    for (int i = t; i < 1024; i += 256){
      P[P_W1+i] = ((const float*)w1)[i];
      P[P_W2+i] = ((const float*)w2)[i];
    }
    if (t < 8){
      P[P_TEMP+t] = ((const float*)temp)[t];
      P[P_B1+t]   = ((const float*)b1)[t];
      P[P_S1+t]   = ((const float*)s1)[t];
      P[P_BB1+t]  = ((const float*)bb1)[t];
    }
  } else {
    for (int i = t; i < 128; i += 256){
      P[P_CB+i]  = bu2f(((const u16*)cb)[i]);
      P[P_BNS+i] = bu2f(((const u16*)bns)[i]);
      P[P_BNB+i] = bu2f(((const u16*)bnb)[i]);
      P[P_B2+i]  = bu2f(((const u16*)b2)[i]);
    }
    for (int i = t; i < 1024; i += 256){
      P[P_W1+i] = bu2f(((const u16*)w1)[i]);
      P[P_W2+i] = bu2f(((const u16*)w2)[i]);
    }
    if (t < 8){
      P[P_TEMP+t] = bu2f(((const u16*)temp)[t]);
      P[P_B1+t]   = bu2f(((const u16*)b1)[t]);
      P[P_S1+t]   = bu2f(((const u16*)s1)[t]);
      P[P_BB1+t]  = bu2f(((const u16*)bb1)[t]);
    }
  }
}

// ===================== weight prep for MFMA conv =====================
__global__ void k_wprep2(const void* __restrict__ w, u16* __restrict__ wT2,
                         const float* __restrict__ prm, const int* __restrict__ flg){
  const int f32 = *flg;
  int U = blockIdx.x*256 + threadIdx.x;
  if (U < 294912){
    int j = U & 7;
    int E = U >> 3;
    int n = E & 127;
    int o = (E >> 7) & 3;
    int tc = E >> 9;
    int chunk = tc & 7, tap = tc >> 3;
    int c = chunk*32 + o*8 + j;
    int src = n*2304 + c*9 + tap;
    float v = f32 ? ((const float*)w)[src] : bu2f(((const u16*)w)[src]);
    wT2[U] = f2bu(v * prm[P_BNS + n]);
  }
}

// ===================== x transpose: NCHW -> [b][h][w][c] bf16 =====================
__global__ __launch_bounds__(256) void k_trans(const void* __restrict__ x, u16* __restrict__ xt,
                                               const int* __restrict__ flg){
  __shared__ u16 L[256*66];
  const int t = threadIdx.x;
  const int b = blockIdx.x >> 6, h = blockIdx.x & 63;
  const int f32m = __builtin_amdgcn_readfirstlane(*flg);
  if (f32m){
    const float* xf = (const float*)x;
    for (int i = t; i < 16384; i += 256){
      int c = i >> 6, w = i & 63;
      L[c*66 + w] = f2bu(xf[((b*256 + c)*64 + h)*64 + w]);
    }
  } else {
    const u16* xb = (const u16*)x;
    for (int i = t; i < 16384; i += 256){
      int c = i >> 6, w = i & 63;
      L[c*66 + w] = xb[((b*256 + c)*64 + h)*64 + w];
    }
  }
  __syncthreads();
  u16* dst = xt + ((b*64 + h)*64)*256;
  for (int j = t; j < 16384; j += 256){
    int w = j >> 8, c = j & 255;
    dst[w*256 + c] = L[c*66 + w];
  }
}

// ===================== MFMA implicit-GEMM conv + BN + ReLU =====================
// r7's winner: M-split (acc[2][8], MFMA:A-load = 8:1), single-buffer 64 KB gl_lds
// staging, 2 blocks/CU, XCD decode. Unchanged.
__global__ __launch_bounds__(256) void k_cmm(const u16* __restrict__ xt, const u16* __restrict__ wT2,
                                             const float* __restrict__ prm, u16* __restrict__ A){
  __shared__ __align__(16) uint4 sm4[4096];   // 64 KB single weight buffer
  const int t = threadIdx.x;
  const int blk = blockIdx.x;
  const int bb = (blk & 7) + 8*(blk >> 8);    // xcd = blk&7; bb in {xcd, xcd+8}
  const int mt2 = (blk >> 3) & 31;            // 2-row tile index
  const int lane = t & 63, wave = t >> 6;
  const int wrow = wave >> 1, whalf = wave & 1;
  const int quad = lane >> 4, lr = lane & 15;

  f32x4 acc[2][8];
  #pragma unroll
  for (int mi = 0; mi < 2; ++mi)
    #pragma unroll
    for (int nt = 0; nt < 8; ++nt)
      acc[mi][nt] = (f32x4){0.f,0.f,0.f,0.f};

  const short8 zz = {0,0,0,0,0,0,0,0};

  for (int tap = 0; tap < 9; ++tap){
    const int ky = tap/3, kx = tap - ky*3;
    __syncthreads();   // all waves done reading previous tap's buffer
    {
      const uint4* src = (const uint4*)(wT2 + tap*32768);
      #pragma unroll
      for (int i = 0; i < 16; ++i) gl_lds16(&src[t + 256*i], &sm4[t + 256*i]);
    }
    __syncthreads();   // vmcnt(0) drain + barrier

    const u16* smB = (const u16*)sm4;
    const int hg = mt2*2 + wrow + 3*ky - 3;
    const bool hok = ((unsigned)hg < 64u);
    const u16* abase = xt + ((bb*64 + hg)*64)*256 + quad*8;

    for (int chunk = 0; chunk < 8; ++chunk){
      short8 av[2];
      #pragma unroll
      for (int mi = 0; mi < 2; ++mi){
        const int wg = whalf*32 + mi*16 + lr + 3*kx - 3;
        short8 v = zz;
        if (hok && ((unsigned)wg < 64u))
          v = *(const short8*)(abase + wg*256 + chunk*32);
        av[mi] = v;
      }
      short8 bv[8];
      #pragma unroll
      for (int nt = 0; nt < 8; ++nt)
        bv[nt] = *(const short8*)(smB + (chunk*512 + quad*128 + nt*16 + lr)*8);
      #pragma unroll
      for (int mi = 0; mi < 2; ++mi)
        #pragma unroll
        for (int nt = 0; nt < 8; ++nt)
          acc[mi][nt] = MF(av[mi], bv[nt], acc[mi][nt]);
    }
  }

  // epilogue: transpose through LDS (sm4 reused: 16x133 f32 = 8.5 KB),
  // 8 rounds of 16 channels over M=128 block pixels.
  float* C = (float*)sm4;
  u16* outb = A + (bb*128)*4096 + mt2*128;
  __syncthreads();
  for (int nt = 0; nt < 8; ++nt){
    #pragma unroll
    for (int mi = 0; mi < 2; ++mi)
      #pragma unroll
      for (int r = 0; r < 4; ++r){
        const int m = wrow*64 + whalf*32 + mi*16 + quad*4 + r;
        C[lr*133 + m] = acc[mi][nt][r];
      }
    __syncthreads();
    #pragma unroll
    for (int i = 0; i < 8; ++i){
      const int idx = i*256 + t;
      const int dd = idx >> 7, m = idx & 127;
      const int d = nt*16 + dd;
      const float bi = prm[P_CB + d]*prm[P_BNS + d] + prm[P_BNB + d];
      const float v = fmaxf(C[dd*133 + m] + bi, 0.f);
      outb[d*4096 + m] = f2bu(v);
    }
    __syncthreads();
  }
}

// ===================== fft2 via MFMA: F = E*img*E per (b,c) =====================
// r8: hoisted global loads (r7 counters showed VGPR=40 lean schedule with all
// pipes idle — serialize loads->compute; explicit register arrays force ILP).
__global__ __launch_bounds__(256) void k_fft2_m(const u16* __restrict__ A, u16* __restrict__ Frb,
                                                u16* __restrict__ Fib, const u16* __restrict__ dft){
  __shared__ __align__(16) u16 TTr[64*72], TTi[64*72];
  const int bc = blockIdx.x, t = threadIdx.x;
  const int lane = t & 63, wave = t >> 6;
  const int quad = lane >> 4, lr = lane & 15;
  const u16* EFr = dft;
  const u16* EFi = dft + 4096;
  const u16* img = A + bc*4096;

  // ---- hoisted loads: all pass1 inputs in flight before any compute ----
  short8 av[4][2];
  #pragma unroll
  for (int mi = 0; mi < 4; ++mi)
    #pragma unroll
    for (int ks = 0; ks < 2; ++ks)
      av[mi][ks] = *(const short8*)(img + (mi*16+lr)*64 + ks*32 + quad*8);
  short8 e1r[2], e1i[2];
  #pragma unroll
  for (int ks = 0; ks < 2; ++ks){
    const int bo = (wave*16+lr)*64 + ks*32 + quad*8;
    e1r[ks] = *(const short8*)(EFr + bo);
    e1i[ks] = *(const short8*)(EFi + bo);
  }

  // pass1: T[h][k2] = sum_w img[h][w] E[k2][w]; store T^T[k2][h] (k2-tile = wave)
  #pragma unroll
  for (int mi = 0; mi < 4; ++mi){
    f32x4 ar = {0.f,0.f,0.f,0.f}, ai = {0.f,0.f,0.f,0.f};
    #pragma unroll
    for (int ks = 0; ks < 2; ++ks){
      ar = MF(av[mi][ks], e1r[ks], ar); ai = MF(av[mi][ks], e1i[ks], ai);
    }
    *(ushort4*)(TTr + (wave*16+lr)*72 + mi*16 + quad*4) = pk4(ar);
    *(ushort4*)(TTi + (wave*16+lr)*72 + mi*16 + quad*4) = pk4(ai);
  }
  __syncthreads();

  // ---- hoisted pass2 inputs: E fragments (global) + nt-invariant TT (LDS) ----
  short8 e2r[4][2], e2i[4][2];
  #pragma unroll
  for (int nt = 0; nt < 4; ++nt)
    #pragma unroll
    for (int ks = 0; ks < 2; ++ks){
      const int bo = (nt*16+lr)*64 + ks*32 + quad*8;
      e2r[nt][ks] = *(const short8*)(EFr + bo);
      e2i[nt][ks] = *(const short8*)(EFi + bo);
    }
  short8 ttr[2], tti[2];
  #pragma unroll
  for (int ks = 0; ks < 2; ++ks){
    ttr[ks] = *(const short8*)(TTr + (wave*16+lr)*72 + ks*32 + quad*8);
    tti[ks] = *(const short8*)(TTi + (wave*16+lr)*72 + ks*32 + quad*8);
  }

  // pass2: F^T[k2][k1] = sum_h T^T[k2][h] E[k1][h]  (k2-tile = wave)
  #pragma unroll
  for (int nt = 0; nt < 4; ++nt){
    f32x4 a1={0.f,0.f,0.f,0.f}, a2={0.f,0.f,0.f,0.f}, a3={0.f,0.f,0.f,0.f}, a4={0.f,0.f,0.f,0.f};
    #pragma unroll
    for (int ks = 0; ks < 2; ++ks){
      a1 = MF(ttr[ks], e2r[nt][ks], a1); a2 = MF(tti[ks], e2i[nt][ks], a2);
      a3 = MF(ttr[ks], e2i[nt][ks], a3); a4 = MF(tti[ks], e2r[nt][ks], a4);
    }
    f32x4 fr, fi;
    #pragma unroll
    for (int r = 0; r < 4; ++r){ fr[r] = a1[r]-a2[r]; fi[r] = a3[r]+a4[r]; }
    // D[m=k2=wave*16+quad*4+r][n=k1=nt*16+lr]; flat = k1*64 + k2
    const int flat = (nt*16+lr)*64 + wave*16 + quad*4;
    *(ushort4*)(Frb + bc*4096 + flat) = pk4(fr);
    *(ushort4*)(Fib + bc*4096 + flat) = pk4(fi);
  }
}

// ===================== attention phase 1: split-K MFMA Gram partials =====================
// grid = 128 (b,h) * 16 n-chunks; each wave owns 64 columns (2 K-steps).
// Partials p1=Ar*Ar^T, p2=Ai*Ai^T, p3=Ar*Ai^T, p4=Ai*Ar^T stored raw so that
// phase 2 recovers gr=p1-p2, gi=p3+p4 AND norms^2[i]=(p1+p2)[i][i] (k_norms is gone).
__global__ __launch_bounds__(256) void k_attn1(const u16* __restrict__ Frb,
                                               const u16* __restrict__ Fib,
                                               float* __restrict__ part){
  __shared__ float R[4][4][256];   // [wave][q][m*16+n]
  const int blk = blockIdx.x;
  const int bh = blk >> 4, chunk = blk & 15;
  const int t = threadIdx.x, lane = t & 63, wave = t >> 6;
  const int quad = lane >> 4, lr = lane & 15;
  const u16* fr = Frb + bh*65536;
  const u16* fi = Fib + bh*65536;
  const int c0 = chunk*256 + wave*64;
  f32x4 a1={0.f,0.f,0.f,0.f}, a2={0.f,0.f,0.f,0.f}, a3={0.f,0.f,0.f,0.f}, a4={0.f,0.f,0.f,0.f};
  #pragma unroll
  for (int ks = 0; ks < 2; ++ks){
    const int off = lr*4096 + c0 + ks*32 + quad*8;
    short8 ar = *(const short8*)(fr + off);
    short8 ai = *(const short8*)(fi + off);
    a1 = MF(ar, ar, a1); a2 = MF(ai, ai, a2);
    a3 = MF(ar, ai, a3); a4 = MF(ai, ar, a4);
  }
  // D[m=quad*4+r][n=lr]
  #pragma unroll
  for (int r = 0; r < 4; ++r){
    const int mn = (quad*4 + r)*16 + lr;
    R[wave][0][mn] = a1[r];
    R[wave][1][mn] = a2[r];
    R[wave][2][mn] = a3[r];
    R[wave][3][mn] = a4[r];
  }
  __syncthreads();
  float* dst = part + blk*1024;
  #pragma unroll
  for (int q = 0; q < 4; ++q)
    dst[q*256 + t] = R[0][q][t] + R[1][q][t] + R[2][q][t] + R[3][q][t];
}

// ===================== attention phase 2: reduce + norms + dual softmax + c-axis ifft fold ===
__global__ __launch_bounds__(256) void k_attn2(const float* __restrict__ part,
                                               const float* __restrict__ prm,
                                               float* __restrict__ wsM){
  __shared__ float AR[16][17], AI[16][17], NR[16];
  const int bh = blockIdx.x;
  const int h = bh & 7;
  const int t = threadIdx.x;
  const float* p = part + bh*16384;
  float s1=0.f, s2=0.f, s3=0.f, s4=0.f;
  #pragma unroll
  for (int ch = 0; ch < 16; ++ch){
    s1 += p[ch*1024 +       t];
    s2 += p[ch*1024 + 256 + t];
    s3 += p[ch*1024 + 512 + t];
    s4 += p[ch*1024 + 768 + t];
  }
  const int m = t >> 4, n = t & 15;
  if (m == n) NR[m] = fmaxf(sqrtf(fmaxf(s1 + s2, 0.f)), 1e-12f);
  __syncthreads();
  const float sc = prm[P_TEMP + h] / (NR[m]*NR[n]);
  AR[m][n] = (s1 - s2)*sc;
  AI[m][n] = (s3 + s4)*sc;
  __syncthreads();
  if (t < 32){
    float* row = (t < 16) ? AR[t & 15] : AI[t & 15];
    float mx = row[0];
    for (int j2 = 1; j2 < 16; ++j2) mx = fmaxf(mx, row[j2]);
    float s = 0.f, e[16];
    for (int j2 = 0; j2 < 16; ++j2){ e[j2] = expf(row[j2] - mx); s += e[j2]; }
    float inv = 1.f/s;
    for (int j2 = 0; j2 < 16; ++j2) row[j2] = e[j2]*inv;
  }
  __syncthreads();
  {
    const int mi = t >> 4, mj = t & 15;
    float mr = 0.f, mim = 0.f;
    #pragma unroll
    for (int pp = 0; pp < 16; ++pp){
      float sv, cv;
      sincospif((float)((mi*pp) & 15)/8.0f, &sv, &cv);
      const float arv = AR[pp][mj], aiv = AI[pp][mj];
      mr  += cv*arv - sv*aiv;
      mim += cv*aiv + sv*arv;
    }
    wsM[bh*512 + t*2]     = mr*(1.f/16.f);
    wsM[bh*512 + t*2 + 1] = mim*(1.f/16.f);
  }
}

// ===================== gating MLP -> g plane (bf16) =====================
__global__ __launch_bounds__(256) void k_gate(const u16* __restrict__ Frb,
                                              const float* __restrict__ prm,
                                              u16* __restrict__ g){
  __shared__ float W1T[128][8];
  __shared__ float W2[128][8];
  __shared__ float B1v[8], S1v[8], BB1v[8];
  __shared__ float B2v[128];
  const int t = threadIdx.x;
  for (int i = t; i < 1024; i += 256){
    W1T[i & 127][i >> 7] = prm[P_W1 + i];
    W2[i >> 3][i & 7]    = prm[P_W2 + i];
  }
  if (t < 8){ B1v[t] = prm[P_B1+t]; S1v[t] = prm[P_S1+t]; BB1v[t] = prm[P_BB1+t]; }
  if (t < 128) B2v[t] = prm[P_B2+t];
  __syncthreads();
  const int pix = blockIdx.x*256 + t;
  const int b = pix >> 12, n = pix & 4095;
  const u16* fr = Frb + b*128*4096 + n;
  float q[8] = {};
  for (int c = 0; c < 128; ++c){
    const float v = bu2f(fr[c*4096]);
    float wa[4], wb[4];
    ld4a(wa, &W1T[c][0]); ld4a(wb, &W1T[c][4]);
    #pragma unroll
    for (int k = 0; k < 4; ++k){ q[k] = fmaf(wa[k], v, q[k]); q[4+k] = fmaf(wb[k], v, q[4+k]); }
  }
  float qa[8];
  #pragma unroll
  for (int k = 0; k < 8; ++k)
    qa[k] = fmaxf(fmaf(q[k] + B1v[k], S1v[k], BB1v[k]), 0.f);
  u16* grow = g + b*128*4096 + n;
  for (int c = 0; c < 128; ++c){
    float wa[4], wb[4];
    ld4a(wa, &W2[c][0]); ld4a(wb, &W2[c][4]);
    float acc = B2v[c];
    #pragma unroll
    for (int k = 0; k < 4; ++k) acc += wa[k]*qa[k] + wb[k]*qa[4+k];
    grow[c*4096] = f2bu(1.f/(1.f + expf(-acc)));
  }
}

// ===================== out_l = |ifft2(g*F)| + x via MFMA (channels 128..255) =====================
// r8: hoisted global loads (x first — HBM-cold; then g/F planes; then E frags).
// r7 counters: VGPR=40, MfmaUtil 4.9%, VALU 26%, HBM 15% at 44% occ — pure
// load-latency serialization. Loads are pure -> bit-identical results.
__global__ __launch_bounds__(256) void k_outl_m(const u16* __restrict__ Frb, const u16* __restrict__ Fib,
                                                const u16* __restrict__ g, const void* __restrict__ x,
                                                float* __restrict__ out, const u16* __restrict__ dft,
                                                const int* __restrict__ flg){
  __shared__ __align__(16) u16 TTr[64*72], TTi[64*72];
  const int bc = blockIdx.x, t = threadIdx.x;
  const int b = bc >> 7, c = bc & 127;
  const int lane = t & 63, wave = t >> 6;
  const int quad = lane >> 4, lr = lane & 15;
  const int f32m = __builtin_amdgcn_readfirstlane(*flg);
  const u16* EIr = dft + 8192;
  const u16* EIi = dft + 12288;
  const u16* pg = g   + bc*4096;
  const u16* pr = Frb + bc*4096;
  const u16* pi = Fib + bc*4096;

  // ---- hoisted loads ----
  float xr[4][4];                          // residual (HBM-cold): issue first
  #pragma unroll
  for (int nt = 0; nt < 4; ++nt){
    const int o = (b*256 + 128 + c)*4096 + (nt*16+lr)*64 + wave*16 + quad*4;
    if (f32m) ld4a(xr[nt], (const float*)x + o); else ld4b(xr[nt], (const u16*)x + o);
  }
  short8 gv[4][2], frv[4][2], fiv[4][2];   // g, Fr, Fi plane fragments
  #pragma unroll
  for (int mi = 0; mi < 4; ++mi)
    #pragma unroll
    for (int ks = 0; ks < 2; ++ks){
      const int ao = (mi*16+lr)*64 + ks*32 + quad*8;
      gv[mi][ks]  = *(const short8*)(pg + ao);
      frv[mi][ks] = *(const short8*)(pr + ao);
      fiv[mi][ks] = *(const short8*)(pi + ao);
    }
  short8 e1r[2], e1i[2];                   // pass1 IDFT fragments
  #pragma unroll
  for (int ks = 0; ks < 2; ++ks){
    const int bo = (wave*16+lr)*64 + ks*32 + quad*8;
    e1r[ks] = *(const short8*)(EIr + bo);
    e1i[ks] = *(const short8*)(EIi + bo);
  }

  // pass1: T[h][k2] = sum_w P[h][w] IF[k2][w], P = g*F; store T^T (k2-tile = wave)
  #pragma unroll
  for (int mi = 0; mi < 4; ++mi){
    f32x4 a1={0.f,0.f,0.f,0.f}, a2={0.f,0.f,0.f,0.f}, a3={0.f,0.f,0.f,0.f}, a4={0.f,0.f,0.f,0.f};
    #pragma unroll
    for (int ks = 0; ks < 2; ++ks){
      short8 apr = mulpk(gv[mi][ks], frv[mi][ks]);
      short8 api = mulpk(gv[mi][ks], fiv[mi][ks]);
      a1 = MF(apr, e1r[ks], a1); a2 = MF(api, e1i[ks], a2);
      a3 = MF(apr, e1i[ks], a3); a4 = MF(api, e1r[ks], a4);
    }
    f32x4 tr, ti;
    #pragma unroll
    for (int r = 0; r < 4; ++r){ tr[r] = a1[r]-a2[r]; ti[r] = a3[r]+a4[r]; }
    *(ushort4*)(TTr + (wave*16+lr)*72 + mi*16 + quad*4) = pk4(tr);
    *(ushort4*)(TTi + (wave*16+lr)*72 + mi*16 + quad*4) = pk4(ti);
  }
  __syncthreads();

  // ---- hoisted pass2 inputs: E fragments (global) + nt-invariant TT (LDS) ----
  short8 e2r[4][2], e2i[4][2];
  #pragma unroll
  for (int nt = 0; nt < 4; ++nt)
    #pragma unroll
    for (int ks = 0; ks < 2; ++ks){
      const int bo = (nt*16+lr)*64 + ks*32 + quad*8;
      e2r[nt][ks] = *(const short8*)(EIr + bo);
      e2i[nt][ks] = *(const short8*)(EIi + bo);
    }
  short8 ttr[2], tti[2];
  #pragma unroll
  for (int ks = 0; ks < 2; ++ks){
    ttr[ks] = *(const short8*)(TTr + (wave*16+lr)*72 + ks*32 + quad*8);
    tti[ks] = *(const short8*)(TTi + (wave*16+lr)*72 + ks*32 + quad*8);
  }

  // pass2: Y^T[k2][k1] = sum_h T^T[k2][h] IF[k1][h]; out = |Y| + x
  #pragma unroll
  for (int nt = 0; nt < 4; ++nt){
    f32x4 a1={0.f,0.f,0.f,0.f}, a2={0.f,0.f,0.f,0.f}, a3={0.f,0.f,0.f,0.f}, a4={0.f,0.f,0.f,0.f};
    #pragma unroll
    for (int ks = 0; ks < 2; ++ks){
      a1 = MF(ttr[ks], e2r[nt][ks], a1); a2 = MF(tti[ks], e2i[nt][ks], a2);
      a3 = MF(ttr[ks], e2i[nt][ks], a3); a4 = MF(tti[ks], e2r[nt][ks], a4);
    }
    // D[m=k2=wave*16+quad*4+r][n=k1=nt*16+lr]
    const int o = (b*256 + 128 + c)*4096 + (nt*16+lr)*64 + wave*16 + quad*4;
    float ov[4];
    #pragma unroll
    for (int r = 0; r < 4; ++r){
      float yr = a1[r]-a2[r], yi = a3[r]+a4[r];
      ov[r] = sqrtf(yr*yr + yi*yi) + xr[nt][r];
    }
    st4(out + o, ov);
  }
}

// ===================== 4096-pt IFFT via MFMA, four-step, in place =====================
// r8: hoisted E fragments + twiddles + pass-invariant LDS fragments (same
// lean-schedule pathology family as k_outl_m).
__global__ __launch_bounds__(256) void k_ifft4096_m(u16* __restrict__ Frb, u16* __restrict__ Fib,
                                                    const float* __restrict__ ws,
                                                    const u16* __restrict__ dft){
  __shared__ __align__(16) u16 A2Tr[64*72], A2Ti[64*72], Cr[64*72], Ci[64*72];
  const int bc = blockIdx.x, t = threadIdx.x;
  const int lane = t & 63, wave = t >> 6;
  const int quad = lane >> 4, lr = lane & 15;
  const u16* EIr = dft + 8192;
  const u16* EIi = dft + 12288;
  const float* twr = ws + TABTW_RE;
  const float* twi = ws + TABTW_IM;
  u16* fr = Frb + bc*4096;
  u16* fi = Fib + bc*4096;
  // stage transpose: A2T[n2][n1] = F[n1][n2]
  for (int i = t; i < 4096; i += 256){
    int n1 = i >> 6, n2 = i & 63;
    A2Tr[n2*72 + n1] = fr[i];
    A2Ti[n2*72 + n1] = fi[i];
  }
  // ---- hoisted (independent of staging): pass1 E fragments + twiddles ----
  short8 e1r[2], e1i[2];
  #pragma unroll
  for (int ks = 0; ks < 2; ++ks){
    const int ao = (wave*16+lr)*64 + ks*32 + quad*8;
    e1r[ks] = *(const short8*)(EIr + ao);
    e1i[ks] = *(const short8*)(EIi + ao);
  }
  float twrv[4][4], twiv[4][4];
  #pragma unroll
  for (int nt = 0; nt < 4; ++nt)
    #pragma unroll
    for (int r = 0; r < 4; ++r){
      const int k1 = wave*16 + quad*4 + r;
      const int n2 = nt*16 + lr;
      twrv[nt][r] = twr[k1*64 + n2];
      twiv[nt][r] = twi[k1*64 + n2];
    }
  __syncthreads();
  // pass1: T[k1][n2] = sum_n1 IF[k1][n1] A2T[n2][n1]; twiddle -> C[k1][n2]  (k1-tile = wave)
  #pragma unroll
  for (int nt = 0; nt < 4; ++nt){
    f32x4 a1={0.f,0.f,0.f,0.f}, a2={0.f,0.f,0.f,0.f}, a3={0.f,0.f,0.f,0.f}, a4={0.f,0.f,0.f,0.f};
    #pragma unroll
    for (int ks = 0; ks < 2; ++ks){
      short8 br = *(const short8*)(A2Tr + (nt*16+lr)*72 + ks*32 + quad*8);
      short8 bi = *(const short8*)(A2Ti + (nt*16+lr)*72 + ks*32 + quad*8);
      a1 = MF(e1r[ks], br, a1); a2 = MF(e1i[ks], bi, a2);
      a3 = MF(e1r[ks], bi, a3); a4 = MF(e1i[ks], br, a4);
    }
    // D[m=k1=wave*16+quad*4+r][n=n2=nt*16+lr]
    #pragma unroll
    for (int r = 0; r < 4; ++r){
      const int k1 = wave*16 + quad*4 + r;
      const int n2 = nt*16 + lr;
      const float trv = a1[r]-a2[r], tiv = a3[r]+a4[r];
      const float wr = twrv[nt][r], wi = twiv[nt][r];
      Cr[k1*72 + n2] = f2bu(trv*wr - tiv*wi);
      Ci[k1*72 + n2] = f2bu(trv*wi + tiv*wr);
    }
  }
  __syncthreads();
  // ---- hoisted pass2 inputs: E fragments (global) + nt-invariant C (LDS) ----
  short8 e2r[4][2], e2i[4][2];
  #pragma unroll
  for (int nt = 0; nt < 4; ++nt)
    #pragma unroll
    for (int ks = 0; ks < 2; ++ks){
      const int bo = (nt*16+lr)*64 + ks*32 + quad*8;
      e2r[nt][ks] = *(const short8*)(EIr + bo);
      e2i[nt][ks] = *(const short8*)(EIi + bo);
    }
  short8 ccr[2], cci[2];
  #pragma unroll
  for (int ks = 0; ks < 2; ++ks){
    ccr[ks] = *(const short8*)(Cr + (wave*16+lr)*72 + ks*32 + quad*8);
    cci[ks] = *(const short8*)(Ci + (wave*16+lr)*72 + ks*32 + quad*8);
  }
  // pass2: Z[k1][k2] = sum_n2 C[k1][n2] IF[k2][n2]; store flat = k2*64 + k1  (k1-tile = wave)
  #pragma unroll
  for (int nt = 0; nt < 4; ++nt){
    f32x4 a1={0.f,0.f,0.f,0.f}, a2={0.f,0.f,0.f,0.f}, a3={0.f,0.f,0.f,0.f}, a4={0.f,0.f,0.f,0.f};
    #pragma unroll
    for (int ks = 0; ks < 2; ++ks){
      a1 = MF(ccr[ks], e2r[nt][ks], a1); a2 = MF(cci[ks], e2i[nt][ks], a2);
      a3 = MF(ccr[ks], e2i[nt][ks], a3); a4 = MF(cci[ks], e2r[nt][ks], a4);
    }
    f32x4 zr, zi;
    #pragma unroll
    for (int r = 0; r < 4; ++r){ zr[r] = a1[r]-a2[r]; zi[r] = a3[r]+a4[r]; }
    // D[m=k1=wave*16+quad*4+r][n=k2=nt*16+lr]; flat = k2*64 + k1 -> 4 consecutive k1
    const int flat = (nt*16+lr)*64 + wave*16 + quad*4;
    *(ushort4*)(fr + flat) = pk4(zr);
    *(ushort4*)(fi + flat) = pk4(zi);
  }
}

// ===================== out_f = |M @ Z| + x  (channels 0..127), f32 out =====================
__global__ __launch_bounds__(256) void k_outf(const u16* __restrict__ Zr, const u16* __restrict__ Zi,
                                              const float* __restrict__ wsM, const void* __restrict__ x,
                                              float* __restrict__ out, const int* __restrict__ flg){
  __shared__ float MreT[16][20], MimT[16][20];
  const int gb = blockIdx.x;
  const int bh = gb & 127, nch = gb >> 7;
  const int b = bh >> 3, h = bh & 7;
  const int t = threadIdx.x;
  const int f32m = __builtin_amdgcn_readfirstlane(*flg);
  {
    const int i = t >> 4, j = t & 15;
    MreT[j][i] = wsM[bh*512 + t*2];
    MimT[j][i] = wsM[bh*512 + t*2 + 1];
  }
  __syncthreads();
  const int i0 = (t & 3)*4;
  const int nn = nch*256 + (t >> 2)*4;
  const u16* zr = Zr + (b*128 + h*16)*4096 + nn;
  const u16* zi = Zi + (b*128 + h*16)*4096 + nn;
  float accr[4][4] = {}, acci[4][4] = {};
  #pragma unroll
  for (int j = 0; j < 16; ++j){
    float mr[4], mi[4], vr[4], vi[4];
    ld4a(mr, &MreT[j][i0]);
    ld4a(mi, &MimT[j][i0]);
    ld4b(vr, zr + j*4096);
    ld4b(vi, zi + j*4096);
    #pragma unroll
    for (int i = 0; i < 4; ++i)
      #pragma unroll
      for (int n = 0; n < 4; ++n){
        accr[i][n] += mr[i]*vr[n] - mi[i]*vi[n];
        acci[i][n] += mr[i]*vi[n] + mi[i]*vr[n];
      }
  }
  #pragma unroll
  for (int i = 0; i < 4; ++i){
    const int o = (b*256 + h*16 + i0 + i)*4096 + nn;
    float xr[4];
    if (f32m) ld4a(xr, (const float*)x + o); else ld4b(xr, (const u16*)x + o);
    float ov[4];
    #pragma unroll
    for (int n = 0; n < 4; ++n)
      ov[n] = sqrtf(accr[i][n]*accr[i][n] + acci[i][n]*acci[i][n]) + xr[n];
    st4(out + o, ov);
  }
}

// ===================== launch =====================
extern "C" void kernel_launch(void* const* d_in, const int* in_sizes, int n_in,
                              void* d_out, int out_size, void* d_ws, size_t ws_size,
                              hipStream_t stream) {
  const void* x        = d_in[0];
  const void* conv2_w  = d_in[1];
  const void* conv2_b  = d_in[2];
  const void* bn2_s    = d_in[3];
  const void* bn2_b    = d_in[4];
  const void* temp     = d_in[5];
  const void* w1_w     = d_in[6];
  const void* w1_b     = d_in[7];
  const void* bnw_s    = d_in[8];
  const void* bnw_b    = d_in[9];
  const void* w2_w     = d_in[10];
  const void* w2_b     = d_in[11];
  float* out = (float*)d_out;
  float* wsf = (float*)d_ws;

  if (ws_size < (size_t)(F32_END*4) + 3u*(size_t)BPLANE*2u) return;

  int* flag = (int*)(wsf + FLAG_OFF);
  float* prm = wsf + PRM_OFF;
  u16* wT2 = (u16*)(wsf + WT_OFF);
  u16* dft = (u16*)(wsf + DFT16_OFF);
  u16* wsb = (u16*)(wsf + F32_END);
  u16* Frb = wsb;
  u16* Fib = wsb + BPLANE;
  u16* xt  = wsb;              // aliases Frb+Fib (dead before k_fft2_m writes them)
  u16* Ab  = wsb + 2*BPLANE;   // conv output; later aliased by partials, then g
  u16* g   = Ab;
  float* part = (float*)Ab;    // 8 MB Gram partials (Ab dead after k_fft2_m;
                               // consumed by k_attn2 before k_gate writes g)

  k_detect<<<1, 64, 0, stream>>>((const u16*)x, flag);
  k_tables<<<16, 256, 0, stream>>>(wsf);
  k_dftprep<<<16, 256, 0, stream>>>(dft);
  k_pack<<<1, 256, 0, stream>>>(conv2_b, bn2_s, bn2_b, temp, w1_w, w1_b, bnw_s, bnw_b,
                                w2_w, w2_b, flag, prm);
  k_wprep2<<<1152, 256, 0, stream>>>(conv2_w, wT2, prm, flag);
  k_trans<<<1024, 256, 0, stream>>>(x, xt, flag);
  k_cmm<<<512, 256, 0, stream>>>(xt, wT2, prm, Ab);
  k_fft2_m<<<2048, 256, 0, stream>>>(Ab, Frb, Fib, dft);
  k_attn1<<<2048, 256, 0, stream>>>(Frb, Fib, part);
  k_attn2<<<128, 256, 0, stream>>>(part, prm, wsf + MMAT_OFF);
  k_gate<<<256, 256, 0, stream>>>(Frb, prm, g);
  k_outl_m<<<2048, 256, 0, stream>>>(Frb, Fib, g, x, out, dft, flag);
  k_ifft4096_m<<<2048, 256, 0, stream>>>(Frb, Fib, wsf, dft);
  k_outf<<<2048, 256, 0, stream>>>(Frb, Fib, wsf + MMAT_OFF, x, out, flag);
}